// Round 12
// baseline (379.298 us; speedup 1.0000x reference)
//
#include <hip/hip_runtime.h>
#include <hip/hip_bf16.h>
#include <math.h>

#define BATCH  2
#define SEQ    2048
#define HID    1024
#define INNER  2048
#define NSTATE 64
#define NTOK   (BATCH * SEQ)
#define TCHUNK 64
#define NCHUNK (SEQ / TCHUNK)
#define NMID   (INNER + 2 * NSTATE)   // 2176
#define LDH    1056                   // HID + 32 (de-aliased row stride)
#define LDI    2080                   // INNER + 32 (de-aliased row stride)

typedef __bf16 bf16x8 __attribute__((ext_vector_type(8)));
typedef float  f32x4  __attribute__((ext_vector_type(4)));

typedef const __attribute__((address_space(1))) char* gas_ptr;
typedef __attribute__((address_space(3))) char*       las_ptr;

__device__ __forceinline__ void gload16(const void* g, void* l) {
  __builtin_amdgcn_global_load_lds((gas_ptr)g, (las_ptr)l, 16, 0, 0);
}

__device__ __forceinline__ unsigned short f2bf(float f) {
  __hip_bfloat16 h = __float2bfloat16(f);
  return __builtin_bit_cast(unsigned short, h);
}
__device__ __forceinline__ float bf2f(unsigned short u) {
  unsigned int x = ((unsigned int)u) << 16;
  return __builtin_bit_cast(float, x);
}

// ---------------------------------------------------------------- cvt fp32->bf16 (padded rows)
__global__ __launch_bounds__(256) void cvt_pad_kernel(
    const float* __restrict__ in, __hip_bfloat16* __restrict__ out, int n4) {
  int i = blockIdx.x * 256 + threadIdx.x;
  if (i >= n4) return;
  const int r = i >> 8;             // HID/4 = 256 groups per row
  const int c = (i & 255) * 4;
  float4 v = *(const float4*)&in[(size_t)r * HID + c];
  ushort4 u;
  u.x = f2bf(v.x); u.y = f2bf(v.y); u.z = f2bf(v.z); u.w = f2bf(v.w);
  *(ushort4*)&out[(size_t)r * LDH + c] = u;
}

// ------------------------------------------------- transpose fp32 [R][C] -> bf16 [C][ostride]
__global__ __launch_bounds__(256) void transpose_cvt_kernel(
    const float* __restrict__ in, __hip_bfloat16* __restrict__ out,
    int R, int C, int ostride) {
  __shared__ float tile[32][33];
  int tx = threadIdx.x & 31, ty = threadIdx.x >> 5;
  int c0 = blockIdx.x * 32, r0 = blockIdx.y * 32;
#pragma unroll
  for (int i = 0; i < 4; ++i)
    tile[ty + 8 * i][tx] = in[(size_t)(r0 + ty + 8 * i) * C + c0 + tx];
  __syncthreads();
#pragma unroll
  for (int i = 0; i < 4; ++i)
    out[(size_t)(c0 + ty + 8 * i) * ostride + r0 + tx] =
        __float2bfloat16(tile[tx][ty + 8 * i]);
}

// ---------------------------------------------------------------- GEMM (r11 structure, strides parameterized)
template <int EPI>
__global__ __launch_bounds__(256, 4) void gemm_bt_kernel(
    const __hip_bfloat16* __restrict__ A, const __hip_bfloat16* __restrict__ Bt,
    int M, int N, int Klen, int ldk, int gridN, int nwg, int mnwg,
    float* __restrict__ Cout, int ldc, int ldo,
    __hip_bfloat16* __restrict__ o0, __hip_bfloat16* __restrict__ o1) {
  __shared__ __align__(16) __hip_bfloat16 As[128 * 64];
  __shared__ __align__(16) __hip_bfloat16 Bs[128 * 64];
  const int tid = threadIdx.x;
  const int lane = tid & 63;
  const int w = tid >> 6;
  const int wr = w >> 1, wc = w & 1;

  const int orig = blockIdx.x;
  const int q8 = nwg >> 3, r8 = nwg & 7;
  const int xcd = orig & 7, seq = orig >> 3;
  const int wg = (xcd < r8 ? xcd * (q8 + 1) : r8 * (q8 + 1) + (xcd - r8) * q8) + seq;
  const int kz = wg / mnwg;
  const int wgr = wg - kz * mnwg;
  const int m0 = (wgr / gridN) * 128;
  const int n0 = (wgr % gridN) * 128;

  const __hip_bfloat16* Ab = A + (size_t)kz * Klen;
  const __hip_bfloat16* Bb = Bt + (size_t)kz * Klen;

  f32x4 acc[4][4];
#pragma unroll
  for (int i = 0; i < 4; ++i)
#pragma unroll
    for (int j = 0; j < 4; ++j)
#pragma unroll
      for (int r2 = 0; r2 < 4; ++r2) acc[i][j][r2] = 0.f;

  const int g8row = lane >> 3;
  const int scol = ((lane & 7) ^ g8row) * 8;
  const __hip_bfloat16* Agp = Ab + (size_t)(m0 + w * 32 + g8row) * ldk + scol;
  const __hip_bfloat16* Bgp = Bb + (size_t)(n0 + w * 32 + g8row) * ldk + scol;
  __hip_bfloat16* lA = As + (w * 32) * 64;
  __hip_bfloat16* lB = Bs + (w * 32) * 64;

  const int lrow = lane & 15, lk = lane >> 4;
  const int arow0 = wr * 64 + lrow;
  const int brow0 = wc * 64 + lrow;

  const int nt = Klen >> 6;
  for (int t = 0; t < nt; ++t) {
    __syncthreads();
#pragma unroll
    for (int g = 0; g < 4; ++g) {
      gload16(Agp + (size_t)(g * 8) * ldk + t * 64, lA + (g * 8) * 64);
      gload16(Bgp + (size_t)(g * 8) * ldk + t * 64, lB + (g * 8) * 64);
    }
    __syncthreads();
#pragma unroll
    for (int ss = 0; ss < 2; ++ss) {
      bf16x8 af[4], bv[4];
#pragma unroll
      for (int i = 0; i < 4; ++i) {
        const int ra = arow0 + i * 16;
        af[i] = *(const bf16x8*)(As + ra * 64 + (((ss * 4 + lk) ^ (ra & 7)) * 8));
        const int rb = brow0 + i * 16;
        bv[i] = *(const bf16x8*)(Bs + rb * 64 + (((ss * 4 + lk) ^ (rb & 7)) * 8));
      }
#pragma unroll
      for (int i = 0; i < 4; ++i)
#pragma unroll
        for (int j = 0; j < 4; ++j)
          acc[i][j] = __builtin_amdgcn_mfma_f32_16x16x32_bf16(af[i], bv[j], acc[i][j], 0, 0, 0);
    }
  }

#pragma unroll
  for (int i = 0; i < 4; ++i) {
#pragma unroll
    for (int j = 0; j < 4; ++j) {
#pragma unroll
      for (int r2 = 0; r2 < 4; ++r2) {
        const int row = m0 + wr * 64 + i * 16 + lk * 4 + r2;
        const int col = n0 + wc * 64 + j * 16 + lrow;
        const float v = acc[i][j][r2];
        if constexpr (EPI == 0) {
          Cout[(size_t)kz * M * ldc + (size_t)row * ldc + col] = v;
        } else {
          if (col < INNER) o0[(size_t)row * ldo + col] = __float2bfloat16(v);
          else             o1[(size_t)row * ldo + (col - INNER)] = __float2bfloat16(v);
        }
      }
    }
  }
}

// ---------------------------------------------------------------- mid reduce: P0+P1 -> softplus/dt | Bm | Cm
__global__ __launch_bounds__(256) void reduce_mid_kernel(
    const float* __restrict__ P, const float* __restrict__ bdt,
    float* __restrict__ dtb, float* __restrict__ Bm, float* __restrict__ Cm) {
  const int i = blockIdx.x * 256 + threadIdx.x;
  const int row = i / (NMID / 4);
  const int c4 = i - row * (NMID / 4);
  const int col = c4 * 4;
  const size_t off = (size_t)row * NMID + col;
  float4 a = *(const float4*)&P[off];
  float4 b = *(const float4*)&P[(size_t)NTOK * NMID + off];
  float4 v = make_float4(a.x + b.x, a.y + b.y, a.z + b.z, a.w + b.w);
  if (col < INNER) {
    float4 bb = *(const float4*)&bdt[col];
    float4 d;
    d.x = v.x + bb.x; d.y = v.y + bb.y; d.z = v.z + bb.z; d.w = v.w + bb.w;
    d.x = (d.x > 15.f) ? d.x : log1pf(__expf(d.x));
    d.y = (d.y > 15.f) ? d.y : log1pf(__expf(d.y));
    d.z = (d.z > 15.f) ? d.z : log1pf(__expf(d.z));
    d.w = (d.w > 15.f) ? d.w : log1pf(__expf(d.w));
    *(float4*)&dtb[(size_t)row * LDI + col] = d;
  } else if (col < INNER + NSTATE) {
    *(float4*)&Bm[(size_t)row * NSTATE + (col - INNER)] = v;
  } else {
    *(float4*)&Cm[(size_t)row * NSTATE + (col - INNER - NSTATE)] = v;
  }
}

// ---------------------------------------------------------------- split-K4 reduce (fp32)
__global__ __launch_bounds__(256) void reduce4_kernel(
    const float* __restrict__ P, float* __restrict__ out, int n4) {
  int i = blockIdx.x * 256 + threadIdx.x;
  if (i >= n4) return;
  float4 a = ((const float4*)P)[i];
  float4 b = ((const float4*)P)[i + n4];
  float4 c = ((const float4*)P)[i + 2 * n4];
  float4 d = ((const float4*)P)[i + 3 * n4];
  ((float4*)out)[i] = make_float4((a.x + b.x) + (c.x + d.x), (a.y + b.y) + (c.y + d.y),
                                  (a.z + b.z) + (c.z + d.z), (a.w + b.w) + (c.w + d.w));
}

// ---------------------------------------------------------------- causal depthwise conv + silu (padded strides)
__global__ __launch_bounds__(256) void conv_silu_kernel(
    const __hip_bfloat16* __restrict__ xin, const float* __restrict__ cw,
    const float* __restrict__ cb, __hip_bfloat16* __restrict__ xch) {
  int idx = blockIdx.x * 256 + threadIdx.x;
  int cg = idx & 511;
  int tok = idx >> 9;
  int c = cg * 4;
  int l = tok & (SEQ - 1);
  float wv[4][4];
#pragma unroll
  for (int i = 0; i < 4; ++i) {
    float4 w = *(const float4*)&cw[(c + i) * 4];
    wv[i][0] = w.x; wv[i][1] = w.y; wv[i][2] = w.z; wv[i][3] = w.w;
  }
  float4 bias = *(const float4*)&cb[c];
  float r0 = bias.x, r1 = bias.y, r2 = bias.z, r3 = bias.w;
#pragma unroll
  for (int k = 0; k < 4; ++k) {
    const int d = 3 - k;
    if (l >= d) {
      ushort4 xv = *(const ushort4*)&xin[(size_t)(tok - d) * LDI + c];
      r0 = fmaf(bf2f(xv.x), wv[0][k], r0);
      r1 = fmaf(bf2f(xv.y), wv[1][k], r1);
      r2 = fmaf(bf2f(xv.z), wv[2][k], r2);
      r3 = fmaf(bf2f(xv.w), wv[3][k], r3);
    }
  }
  r0 = r0 / (1.f + __expf(-r0));
  r1 = r1 / (1.f + __expf(-r1));
  r2 = r2 / (1.f + __expf(-r2));
  r3 = r3 / (1.f + __expf(-r3));
  ushort4 u;
  u.x = f2bf(r0); u.y = f2bf(r1); u.z = f2bf(r2); u.w = f2bf(r3);
  *(ushort4*)&xch[(size_t)tok * LDI + c] = u;
}

// ---------------------------------------------------------------- scan phase 1: 2 threads/channel (padded strides)
__global__ __launch_bounds__(256, 4) void scan_state_kernel(
    const float* __restrict__ dtb, const __hip_bfloat16* __restrict__ xch,
    const float* __restrict__ Bm,
    float* __restrict__ S, float* __restrict__ A_chunk) {
  __shared__ float Bsh[TCHUNK][64];
  const int b = blockIdx.z, chunk = blockIdx.y;
  const int tid = threadIdx.x;
  const int h = tid & 1;
  const int c = blockIdx.x * 128 + (tid >> 1);
  const int t0 = chunk * TCHUNK;
  for (int i = tid; i < TCHUNK * 16; i += 256) {
    const int row = i >> 4, q = i & 15;
    *(float4*)&Bsh[row][q * 4] =
        *(const float4*)&Bm[((size_t)(b * SEQ + t0 + row)) * NSTATE + q * 4];
  }
  __syncthreads();
  float s[32];
#pragma unroll
  for (int n = 0; n < 32; ++n) s[n] = 0.f;
  float p = 1.f;
  const size_t basei = (size_t)(b * SEQ + t0) * LDI + c;
  for (int t = 0; t < TCHUNK; ++t) {
    const float dtv = dtb[basei + (size_t)t * LDI];
    const float at = __expf(-dtv);
    const float xc = bf2f(*(const unsigned short*)&xch[basei + (size_t)t * LDI]);
    const float ut = dtv * xc;
    p *= at;
    const float* brow = &Bsh[t][h * 32];
#pragma unroll
    for (int q = 0; q < 8; ++q) {
      const float4 bv = *(const float4*)&brow[q * 4];
      s[4 * q + 0] = fmaf(at, s[4 * q + 0], ut * bv.x);
      s[4 * q + 1] = fmaf(at, s[4 * q + 1], ut * bv.y);
      s[4 * q + 2] = fmaf(at, s[4 * q + 2], ut * bv.z);
      s[4 * q + 3] = fmaf(at, s[4 * q + 3], ut * bv.w);
    }
  }
  const size_t sbase = ((size_t)(b * NCHUNK + chunk) * INNER + c) * NSTATE + h * 32;
#pragma unroll
  for (int q = 0; q < 8; ++q)
    *(float4*)&S[sbase + 4 * q] =
        make_float4(s[4 * q], s[4 * q + 1], s[4 * q + 2], s[4 * q + 3]);
  if (h == 0) A_chunk[(size_t)(b * NCHUNK + chunk) * INNER + c] = p;
}

// ---------------------------------------------------------------- scan phase 2 (in place, unchanged)
__global__ __launch_bounds__(256) void scan_combine_kernel(
    float* __restrict__ S, const float* __restrict__ A_chunk) {
  const int idx = blockIdx.x * 256 + threadIdx.x;
  const int n = idx & 63;
  const int c = (idx >> 6) & (INNER - 1);
  const int b = idx >> 17;
  float s = 0.f;
  for (int k = 0; k < NCHUNK; ++k) {
    const size_t cs = (size_t)(b * NCHUNK + k) * INNER + c;
    const size_t off = cs * NSTATE + n;
    const float loc = S[off];
    S[off] = s;
    s = fmaf(A_chunk[cs], s, loc);
  }
}

// ---------------------------------------------------------------- scan phase 3: 2 threads/channel (padded strides)
__global__ __launch_bounds__(256, 4) void scan_out_kernel(
    const float* __restrict__ dtb, const __hip_bfloat16* __restrict__ xch,
    const float* __restrict__ Bm, const float* __restrict__ Cm,
    const float* __restrict__ S_in, const __hip_bfloat16* __restrict__ zbf,
    const float* __restrict__ Dv, __hip_bfloat16* __restrict__ ygated) {
  __shared__ float Bsh[TCHUNK][64];
  __shared__ float Csh[TCHUNK][64];
  const int b = blockIdx.z, chunk = blockIdx.y;
  const int tid = threadIdx.x;
  const int h = tid & 1;
  const int c = blockIdx.x * 128 + (tid >> 1);
  const int t0 = chunk * TCHUNK;
  for (int i = tid; i < TCHUNK * 16; i += 256) {
    const int row = i >> 4, q = i & 15;
    const size_t src = ((size_t)(b * SEQ + t0 + row)) * NSTATE + q * 4;
    *(float4*)&Bsh[row][q * 4] = *(const float4*)&Bm[src];
    *(float4*)&Csh[row][q * 4] = *(const float4*)&Cm[src];
  }
  __syncthreads();
  float s[32];
  const size_t sbase = ((size_t)(b * NCHUNK + chunk) * INNER + c) * NSTATE + h * 32;
#pragma unroll
  for (int q = 0; q < 8; ++q) {
    const float4 v = *(const float4*)&S_in[sbase + 4 * q];
    s[4 * q] = v.x; s[4 * q + 1] = v.y; s[4 * q + 2] = v.z; s[4 * q + 3] = v.w;
  }
  const float Dc = Dv[c];
  const size_t basei = (size_t)(b * SEQ + t0) * LDI + c;
  for (int t = 0; t < TCHUNK; ++t) {
    const float dtv = dtb[basei + (size_t)t * LDI];
    const float at = __expf(-dtv);
    const float xc = bf2f(*(const unsigned short*)&xch[basei + (size_t)t * LDI]);
    const float ut = dtv * xc;
    const float* brow = &Bsh[t][h * 32];
    const float* crow = &Csh[t][h * 32];
    float y0 = 0.f, y1 = 0.f, y2 = 0.f, y3 = 0.f;
#pragma unroll
    for (int q = 0; q < 8; ++q) {
      const float4 bv = *(const float4*)&brow[q * 4];
      const float4 cv = *(const float4*)&crow[q * 4];
      s[4 * q + 0] = fmaf(at, s[4 * q + 0], ut * bv.x);
      s[4 * q + 1] = fmaf(at, s[4 * q + 1], ut * bv.y);
      s[4 * q + 2] = fmaf(at, s[4 * q + 2], ut * bv.z);
      s[4 * q + 3] = fmaf(at, s[4 * q + 3], ut * bv.w);
      y0 = fmaf(s[4 * q + 0], cv.x, y0);
      y1 = fmaf(s[4 * q + 1], cv.y, y1);
      y2 = fmaf(s[4 * q + 2], cv.z, y2);
      y3 = fmaf(s[4 * q + 3], cv.w, y3);
    }
    float y = (y0 + y1) + (y2 + y3);
    y += __shfl_xor(y, 1);
    if (h == 0) {
      const float yt = fmaf(Dc, xc, y);
      const float z = bf2f(*(const unsigned short*)&zbf[basei + (size_t)t * LDI]);
      const float g = z / (1.f + __expf(-z));
      *(unsigned short*)&ygated[basei + (size_t)t * LDI] = f2bf(yt * g);
    }
  }
}

// ---------------------------------------------------------------- launch
extern "C" void kernel_launch(void* const* d_in, const int* in_sizes, int n_in,
                              void* d_out, int out_size, void* d_ws, size_t ws_size,
                              hipStream_t stream) {
  const float* x      = (const float*)d_in[0];
  const float* W_in   = (const float*)d_in[1];
  const float* conv_w = (const float*)d_in[2];
  const float* conv_b = (const float*)d_in[3];
  const float* W_dt   = (const float*)d_in[4];
  const float* b_dt   = (const float*)d_in[5];
  const float* W_B    = (const float*)d_in[6];
  const float* W_C    = (const float*)d_in[7];
  const float* Dvec   = (const float*)d_in[8];
  const float* W_out  = (const float*)d_in[9];
  float* out = (float*)d_out;

  char* p = (char*)d_ws;
  auto alloc = [&](size_t bytes) {
    char* r = p;
    p += (bytes + 255) & ~(size_t)255;
    return r;
  };
  __hip_bfloat16* xin   = (__hip_bfloat16*)alloc((size_t)NTOK * LDI * 2);  // later ygated
  __hip_bfloat16* zbf   = (__hip_bfloat16*)alloc((size_t)NTOK * LDI * 2);
  char*           scr   = alloc((size_t)NTOK * LDH * 2 + (size_t)2 * INNER * LDH * 2);  // x_bf+WinT; later xch
  __hip_bfloat16* WmidT = (__hip_bfloat16*)alloc((size_t)NMID * LDI * 2);
  __hip_bfloat16* WoutT = (__hip_bfloat16*)alloc((size_t)HID * LDI * 2);
  float*          dtb   = (float*)alloc((size_t)NTOK * LDI * 4);
  float*          Bm    = (float*)alloc((size_t)NTOK * NSTATE * 4);
  float*          Cm    = (float*)alloc((size_t)NTOK * NSTATE * 4);
  float*          Pmid  = (float*)alloc((size_t)2 * NTOK * NMID * 4);   // later S, Pout
  float*          A_chk = (float*)alloc((size_t)BATCH * NCHUNK * INNER * 4);

  __hip_bfloat16* x_bf   = (__hip_bfloat16*)scr;
  __hip_bfloat16* WinT   = (__hip_bfloat16*)(scr + (size_t)NTOK * LDH * 2);
  __hip_bfloat16* xch    = (__hip_bfloat16*)scr;   // NTOK*LDI*2 <= scr size
  __hip_bfloat16* ygated = xin;
  float*          S      = Pmid;
  float*          Pout   = Pmid;

  // 1. conversions / transposes (padded output strides)
  cvt_pad_kernel<<<(NTOK * HID / 4 + 255) / 256, 256, 0, stream>>>(x, x_bf, NTOK * HID / 4);
  transpose_cvt_kernel<<<dim3((2 * INNER) / 32, HID / 32), 256, 0, stream>>>(W_in, WinT, HID, 2 * INNER, LDH);
  transpose_cvt_kernel<<<dim3(INNER / 32, INNER / 32), 256, 0, stream>>>(W_dt, WmidT, INNER, INNER, LDI);
  transpose_cvt_kernel<<<dim3(NSTATE / 32, INNER / 32), 256, 0, stream>>>(
      W_B, WmidT + (size_t)INNER * LDI, INNER, NSTATE, LDI);
  transpose_cvt_kernel<<<dim3(NSTATE / 32, INNER / 32), 256, 0, stream>>>(
      W_C, WmidT + (size_t)(INNER + NSTATE) * LDI, INNER, NSTATE, LDI);
  transpose_cvt_kernel<<<dim3(HID / 32, INNER / 32), 256, 0, stream>>>(W_out, WoutT, INNER, HID, LDI);

  // 2. xz = x @ W_in -> split bf16 (xin | z)
  {
    const int gridN = (2 * INNER) / 128, nwg = (NTOK / 128) * gridN;
    gemm_bt_kernel<1><<<nwg, 256, 0, stream>>>(
        x_bf, WinT, NTOK, 2 * INNER, HID, LDH, gridN, nwg, nwg, nullptr, 0, LDI, xin, zbf);
  }

  // 3. conv + silu
  conv_silu_kernel<<<(NTOK * (INNER / 4)) / 256, 256, 0, stream>>>(xin, conv_w, conv_b, xch);

  // 4. mid GEMM split-K x2 + fused reduce/softplus
  {
    const int gridN = NMID / 128;
    const int mnwg = (NTOK / 128) * gridN;
    const int nwg = mnwg * 2;
    gemm_bt_kernel<0><<<nwg, 256, 0, stream>>>(
        xch, WmidT, NTOK, NMID, INNER / 2, LDI, gridN, nwg, mnwg, Pmid, NMID, 0,
        nullptr, nullptr);
    reduce_mid_kernel<<<(NTOK * (NMID / 4)) / 256, 256, 0, stream>>>(Pmid, b_dt, dtb, Bm, Cm);
  }

  // 5. chunked selective scan (2 threads/channel)
  scan_state_kernel<<<dim3(INNER / 128, NCHUNK, BATCH), 256, 0, stream>>>(dtb, xch, Bm, S, A_chk);
  scan_combine_kernel<<<(BATCH * INNER * NSTATE) / 256, 256, 0, stream>>>(S, A_chk);
  scan_out_kernel<<<dim3(INNER / 128, NCHUNK, BATCH), 256, 0, stream>>>(
      dtb, xch, Bm, Cm, S, zbf, Dvec, ygated);

  // 6. out = ygated @ W_out, split-K x4 + reduce
  {
    const int gridN = HID / 128;
    const int mnwg = (NTOK / 128) * gridN;
    const int nwg = mnwg * 4;
    gemm_bt_kernel<0><<<nwg, 256, 0, stream>>>(
        ygated, WoutT, NTOK, HID, INNER / 4, LDI, gridN, nwg, mnwg, Pout, HID, 0,
        nullptr, nullptr);
    const int n4 = NTOK * HID / 4;
    reduce4_kernel<<<(n4 + 255) / 256, 256, 0, stream>>>(Pout, out, n4);
  }
}

// Round 13
// 377.602 us; speedup vs baseline: 1.0045x; 1.0045x over previous
//
#include <hip/hip_runtime.h>
#include <hip/hip_bf16.h>
#include <math.h>

#define BATCH  2
#define SEQ    2048
#define HID    1024
#define INNER  2048
#define NSTATE 64
#define NTOK   (BATCH * SEQ)
#define TCHUNK 64
#define NCHUNK (SEQ / TCHUNK)
#define NMID   (INNER + 2 * NSTATE)   // 2176
#define LDH    1056
#define LDI    2080

typedef __bf16 bf16x8 __attribute__((ext_vector_type(8)));
typedef float  f32x4  __attribute__((ext_vector_type(4)));

typedef const __attribute__((address_space(1))) char* gas_ptr;
typedef __attribute__((address_space(3))) char*       las_ptr;

__device__ __forceinline__ void gload16(const void* g, void* l) {
  __builtin_amdgcn_global_load_lds((gas_ptr)g, (las_ptr)l, 16, 0, 0);
}

__device__ __forceinline__ unsigned short f2bf(float f) {
  __hip_bfloat16 h = __float2bfloat16(f);
  return __builtin_bit_cast(unsigned short, h);
}
__device__ __forceinline__ float bf2f(unsigned short u) {
  unsigned int x = ((unsigned int)u) << 16;
  return __builtin_bit_cast(float, x);
}

// ---------------------------------------------------------------- cvt fp32->bf16 (padded rows)
__global__ __launch_bounds__(256) void cvt_pad_kernel(
    const float* __restrict__ in, __hip_bfloat16* __restrict__ out, int n4) {
  int i = blockIdx.x * 256 + threadIdx.x;
  if (i >= n4) return;
  const int r = i >> 8;
  const int c = (i & 255) * 4;
  float4 v = *(const float4*)&in[(size_t)r * HID + c];
  ushort4 u;
  u.x = f2bf(v.x); u.y = f2bf(v.y); u.z = f2bf(v.z); u.w = f2bf(v.w);
  *(ushort4*)&out[(size_t)r * LDH + c] = u;
}

// ------------------------------------------------- transpose fp32 [R][C] -> bf16 [C][ostride]
__global__ __launch_bounds__(256) void transpose_cvt_kernel(
    const float* __restrict__ in, __hip_bfloat16* __restrict__ out,
    int R, int C, int ostride) {
  __shared__ float tile[32][33];
  int tx = threadIdx.x & 31, ty = threadIdx.x >> 5;
  int c0 = blockIdx.x * 32, r0 = blockIdx.y * 32;
#pragma unroll
  for (int i = 0; i < 4; ++i)
    tile[ty + 8 * i][tx] = in[(size_t)(r0 + ty + 8 * i) * C + c0 + tx];
  __syncthreads();
#pragma unroll
  for (int i = 0; i < 4; ++i)
    out[(size_t)(c0 + ty + 8 * i) * ostride + r0 + tx] =
        __float2bfloat16(tile[tx][ty + 8 * i]);
}

// ---------------------------------------------------------------- GEMM: 256x128 tile, BK=64
// 8 waves (4M x 2N), per-wave 64x64 out (identical inner structure to r12's verified kernel).
// Staging: 384 rows (256 A + 128 B), 6 gload16/wave, wave-uniform A/B select per (w,g).
// Split-K via mnwg. EPI 0: fp32 -> Cout. EPI 1: bf16 split xin|z.
template <int EPI>
__global__ __launch_bounds__(512, 4) void gemm_bt_kernel(
    const __hip_bfloat16* __restrict__ A, const __hip_bfloat16* __restrict__ Bt,
    int M, int N, int Klen, int ldk, int gridN, int nwg, int mnwg,
    float* __restrict__ Cout, int ldc, int ldo,
    __hip_bfloat16* __restrict__ o0, __hip_bfloat16* __restrict__ o1) {
  __shared__ __align__(16) __hip_bfloat16 As[256 * 64];   // 32 KB
  __shared__ __align__(16) __hip_bfloat16 Bs[128 * 64];   // 16 KB
  const int tid = threadIdx.x;
  const int lane = tid & 63;
  const int w = tid >> 6;           // 0..7
  const int wr = w >> 1;            // 0..3  (M quarter)
  const int wc = w & 1;             // 0..1  (N half)

  // bijective XCD swizzle (m204)
  const int orig = blockIdx.x;
  const int q8 = nwg >> 3, r8 = nwg & 7;
  const int xcd = orig & 7, seq = orig >> 3;
  const int wg = (xcd < r8 ? xcd * (q8 + 1) : r8 * (q8 + 1) + (xcd - r8) * q8) + seq;
  const int kz = wg / mnwg;
  const int wgr = wg - kz * mnwg;
  const int m0 = (wgr / gridN) * 256;
  const int n0 = (wgr % gridN) * 128;

  const __hip_bfloat16* Ab = A + (size_t)kz * Klen;
  const __hip_bfloat16* Bb = Bt + (size_t)kz * Klen;

  f32x4 acc[4][4];
#pragma unroll
  for (int i = 0; i < 4; ++i)
#pragma unroll
    for (int j = 0; j < 4; ++j)
#pragma unroll
      for (int r2 = 0; r2 < 4; ++r2) acc[i][j][r2] = 0.f;

  // staging descriptors: 6 gload16 per wave, 8 rows each (64 lanes x 16B).
  // global source col pre-swizzled (lane&7)^(lane>>3); LDS dest linear.
  const int g8row = lane >> 3;
  const int scol = ((lane & 7) ^ g8row) * 8;
  const __hip_bfloat16* gp[6];
  __hip_bfloat16* lp[6];
#pragma unroll
  for (int g = 0; g < 6; ++g) {
    const int base = w * 48 + g * 8;          // 0..376, uniform per (w,g)
    const bool isA = (base < 256);
    const int rg = isA ? (m0 + base) : (n0 + (base - 256));
    gp[g] = (isA ? Ab : Bb) + (size_t)(rg + g8row) * ldk + scol;
    lp[g] = isA ? (As + base * 64) : (Bs + (base - 256) * 64);
  }

  const int lrow = lane & 15, lk = lane >> 4;
  const int arow0 = wr * 64 + lrow;
  const int brow0 = wc * 64 + lrow;

  const int nt = Klen >> 6;
  for (int t = 0; t < nt; ++t) {
    __syncthreads();
#pragma unroll
    for (int g = 0; g < 6; ++g) gload16(gp[g] + t * 64, lp[g]);
    __syncthreads();   // drains vmcnt(0): tile visible to all waves
#pragma unroll
    for (int ss = 0; ss < 2; ++ss) {
      bf16x8 af[4], bv[4];
#pragma unroll
      for (int i = 0; i < 4; ++i) {
        const int ra = arow0 + i * 16;
        af[i] = *(const bf16x8*)(As + ra * 64 + (((ss * 4 + lk) ^ (ra & 7)) * 8));
        const int rb = brow0 + i * 16;
        bv[i] = *(const bf16x8*)(Bs + rb * 64 + (((ss * 4 + lk) ^ (rb & 7)) * 8));
      }
#pragma unroll
      for (int i = 0; i < 4; ++i)
#pragma unroll
        for (int j = 0; j < 4; ++j)
          acc[i][j] = __builtin_amdgcn_mfma_f32_16x16x32_bf16(af[i], bv[j], acc[i][j], 0, 0, 0);
    }
  }

#pragma unroll
  for (int i = 0; i < 4; ++i) {
#pragma unroll
    for (int j = 0; j < 4; ++j) {
#pragma unroll
      for (int r2 = 0; r2 < 4; ++r2) {
        const int row = m0 + wr * 64 + i * 16 + lk * 4 + r2;
        const int col = n0 + wc * 64 + j * 16 + lrow;
        const float v = acc[i][j][r2];
        if constexpr (EPI == 0) {
          Cout[(size_t)kz * M * ldc + (size_t)row * ldc + col] = v;
        } else {
          if (col < INNER) o0[(size_t)row * ldo + col] = __float2bfloat16(v);
          else             o1[(size_t)row * ldo + (col - INNER)] = __float2bfloat16(v);
        }
      }
    }
  }
}

// ---------------------------------------------------------------- mid reduce: P0+P1 -> softplus/dt | Bm | Cm
__global__ __launch_bounds__(256) void reduce_mid_kernel(
    const float* __restrict__ P, const float* __restrict__ bdt,
    float* __restrict__ dtb, float* __restrict__ Bm, float* __restrict__ Cm) {
  const int i = blockIdx.x * 256 + threadIdx.x;
  const int row = i / (NMID / 4);
  const int c4 = i - row * (NMID / 4);
  const int col = c4 * 4;
  const size_t off = (size_t)row * NMID + col;
  float4 a = *(const float4*)&P[off];
  float4 b = *(const float4*)&P[(size_t)NTOK * NMID + off];
  float4 v = make_float4(a.x + b.x, a.y + b.y, a.z + b.z, a.w + b.w);
  if (col < INNER) {
    float4 bb = *(const float4*)&bdt[col];
    float4 d;
    d.x = v.x + bb.x; d.y = v.y + bb.y; d.z = v.z + bb.z; d.w = v.w + bb.w;
    d.x = (d.x > 15.f) ? d.x : log1pf(__expf(d.x));
    d.y = (d.y > 15.f) ? d.y : log1pf(__expf(d.y));
    d.z = (d.z > 15.f) ? d.z : log1pf(__expf(d.z));
    d.w = (d.w > 15.f) ? d.w : log1pf(__expf(d.w));
    *(float4*)&dtb[(size_t)row * LDI + col] = d;
  } else if (col < INNER + NSTATE) {
    *(float4*)&Bm[(size_t)row * NSTATE + (col - INNER)] = v;
  } else {
    *(float4*)&Cm[(size_t)row * NSTATE + (col - INNER - NSTATE)] = v;
  }
}

// ---------------------------------------------------------------- split-K4 reduce (fp32)
__global__ __launch_bounds__(256) void reduce4_kernel(
    const float* __restrict__ P, float* __restrict__ out, int n4) {
  int i = blockIdx.x * 256 + threadIdx.x;
  if (i >= n4) return;
  float4 a = ((const float4*)P)[i];
  float4 b = ((const float4*)P)[i + n4];
  float4 c = ((const float4*)P)[i + 2 * n4];
  float4 d = ((const float4*)P)[i + 3 * n4];
  ((float4*)out)[i] = make_float4((a.x + b.x) + (c.x + d.x), (a.y + b.y) + (c.y + d.y),
                                  (a.z + b.z) + (c.z + d.z), (a.w + b.w) + (c.w + d.w));
}

// ---------------------------------------------------------------- causal depthwise conv + silu
__global__ __launch_bounds__(256) void conv_silu_kernel(
    const __hip_bfloat16* __restrict__ xin, const float* __restrict__ cw,
    const float* __restrict__ cb, __hip_bfloat16* __restrict__ xch) {
  int idx = blockIdx.x * 256 + threadIdx.x;
  int cg = idx & 511;
  int tok = idx >> 9;
  int c = cg * 4;
  int l = tok & (SEQ - 1);
  float wv[4][4];
#pragma unroll
  for (int i = 0; i < 4; ++i) {
    float4 w = *(const float4*)&cw[(c + i) * 4];
    wv[i][0] = w.x; wv[i][1] = w.y; wv[i][2] = w.z; wv[i][3] = w.w;
  }
  float4 bias = *(const float4*)&cb[c];
  float r0 = bias.x, r1 = bias.y, r2 = bias.z, r3 = bias.w;
#pragma unroll
  for (int k = 0; k < 4; ++k) {
    const int d = 3 - k;
    if (l >= d) {
      ushort4 xv = *(const ushort4*)&xin[(size_t)(tok - d) * LDI + c];
      r0 = fmaf(bf2f(xv.x), wv[0][k], r0);
      r1 = fmaf(bf2f(xv.y), wv[1][k], r1);
      r2 = fmaf(bf2f(xv.z), wv[2][k], r2);
      r3 = fmaf(bf2f(xv.w), wv[3][k], r3);
    }
  }
  r0 = r0 / (1.f + __expf(-r0));
  r1 = r1 / (1.f + __expf(-r1));
  r2 = r2 / (1.f + __expf(-r2));
  r3 = r3 / (1.f + __expf(-r3));
  ushort4 u;
  u.x = f2bf(r0); u.y = f2bf(r1); u.z = f2bf(r2); u.w = f2bf(r3);
  *(ushort4*)&xch[(size_t)tok * LDI + c] = u;
}

// ---------------------------------------------------------------- scan phase 1: 2 threads/channel
__global__ __launch_bounds__(256, 4) void scan_state_kernel(
    const float* __restrict__ dtb, const __hip_bfloat16* __restrict__ xch,
    const float* __restrict__ Bm,
    float* __restrict__ S, float* __restrict__ A_chunk) {
  __shared__ float Bsh[TCHUNK][64];
  const int b = blockIdx.z, chunk = blockIdx.y;
  const int tid = threadIdx.x;
  const int h = tid & 1;
  const int c = blockIdx.x * 128 + (tid >> 1);
  const int t0 = chunk * TCHUNK;
  for (int i = tid; i < TCHUNK * 16; i += 256) {
    const int row = i >> 4, q = i & 15;
    *(float4*)&Bsh[row][q * 4] =
        *(const float4*)&Bm[((size_t)(b * SEQ + t0 + row)) * NSTATE + q * 4];
  }
  __syncthreads();
  float s[32];
#pragma unroll
  for (int n = 0; n < 32; ++n) s[n] = 0.f;
  float p = 1.f;
  const size_t basei = (size_t)(b * SEQ + t0) * LDI + c;
  for (int t = 0; t < TCHUNK; ++t) {
    const float dtv = dtb[basei + (size_t)t * LDI];
    const float at = __expf(-dtv);
    const float xc = bf2f(*(const unsigned short*)&xch[basei + (size_t)t * LDI]);
    const float ut = dtv * xc;
    p *= at;
    const float* brow = &Bsh[t][h * 32];
#pragma unroll
    for (int q = 0; q < 8; ++q) {
      const float4 bv = *(const float4*)&brow[q * 4];
      s[4 * q + 0] = fmaf(at, s[4 * q + 0], ut * bv.x);
      s[4 * q + 1] = fmaf(at, s[4 * q + 1], ut * bv.y);
      s[4 * q + 2] = fmaf(at, s[4 * q + 2], ut * bv.z);
      s[4 * q + 3] = fmaf(at, s[4 * q + 3], ut * bv.w);
    }
  }
  const size_t sbase = ((size_t)(b * NCHUNK + chunk) * INNER + c) * NSTATE + h * 32;
#pragma unroll
  for (int q = 0; q < 8; ++q)
    *(float4*)&S[sbase + 4 * q] =
        make_float4(s[4 * q], s[4 * q + 1], s[4 * q + 2], s[4 * q + 3]);
  if (h == 0) A_chunk[(size_t)(b * NCHUNK + chunk) * INNER + c] = p;
}

// ---------------------------------------------------------------- scan phase 2 (in place)
__global__ __launch_bounds__(256) void scan_combine_kernel(
    float* __restrict__ S, const float* __restrict__ A_chunk) {
  const int idx = blockIdx.x * 256 + threadIdx.x;
  const int n = idx & 63;
  const int c = (idx >> 6) & (INNER - 1);
  const int b = idx >> 17;
  float s = 0.f;
  for (int k = 0; k < NCHUNK; ++k) {
    const size_t cs = (size_t)(b * NCHUNK + k) * INNER + c;
    const size_t off = cs * NSTATE + n;
    const float loc = S[off];
    S[off] = s;
    s = fmaf(A_chunk[cs], s, loc);
  }
}

// ---------------------------------------------------------------- scan phase 3: 2 threads/channel
__global__ __launch_bounds__(256, 4) void scan_out_kernel(
    const float* __restrict__ dtb, const __hip_bfloat16* __restrict__ xch,
    const float* __restrict__ Bm, const float* __restrict__ Cm,
    const float* __restrict__ S_in, const __hip_bfloat16* __restrict__ zbf,
    const float* __restrict__ Dv, __hip_bfloat16* __restrict__ ygated) {
  __shared__ float Bsh[TCHUNK][64];
  __shared__ float Csh[TCHUNK][64];
  const int b = blockIdx.z, chunk = blockIdx.y;
  const int tid = threadIdx.x;
  const int h = tid & 1;
  const int c = blockIdx.x * 128 + (tid >> 1);
  const int t0 = chunk * TCHUNK;
  for (int i = tid; i < TCHUNK * 16; i += 256) {
    const int row = i >> 4, q = i & 15;
    const size_t src = ((size_t)(b * SEQ + t0 + row)) * NSTATE + q * 4;
    *(float4*)&Bsh[row][q * 4] = *(const float4*)&Bm[src];
    *(float4*)&Csh[row][q * 4] = *(const float4*)&Cm[src];
  }
  __syncthreads();
  float s[32];
  const size_t sbase = ((size_t)(b * NCHUNK + chunk) * INNER + c) * NSTATE + h * 32;
#pragma unroll
  for (int q = 0; q < 8; ++q) {
    const float4 v = *(const float4*)&S_in[sbase + 4 * q];
    s[4 * q] = v.x; s[4 * q + 1] = v.y; s[4 * q + 2] = v.z; s[4 * q + 3] = v.w;
  }
  const float Dc = Dv[c];
  const size_t basei = (size_t)(b * SEQ + t0) * LDI + c;
  for (int t = 0; t < TCHUNK; ++t) {
    const float dtv = dtb[basei + (size_t)t * LDI];
    const float at = __expf(-dtv);
    const float xc = bf2f(*(const unsigned short*)&xch[basei + (size_t)t * LDI]);
    const float ut = dtv * xc;
    const float* brow = &Bsh[t][h * 32];
    const float* crow = &Csh[t][h * 32];
    float y0 = 0.f, y1 = 0.f, y2 = 0.f, y3 = 0.f;
#pragma unroll
    for (int q = 0; q < 8; ++q) {
      const float4 bv = *(const float4*)&brow[q * 4];
      const float4 cv = *(const float4*)&crow[q * 4];
      s[4 * q + 0] = fmaf(at, s[4 * q + 0], ut * bv.x);
      s[4 * q + 1] = fmaf(at, s[4 * q + 1], ut * bv.y);
      s[4 * q + 2] = fmaf(at, s[4 * q + 2], ut * bv.z);
      s[4 * q + 3] = fmaf(at, s[4 * q + 3], ut * bv.w);
      y0 = fmaf(s[4 * q + 0], cv.x, y0);
      y1 = fmaf(s[4 * q + 1], cv.y, y1);
      y2 = fmaf(s[4 * q + 2], cv.z, y2);
      y3 = fmaf(s[4 * q + 3], cv.w, y3);
    }
    float y = (y0 + y1) + (y2 + y3);
    y += __shfl_xor(y, 1);
    if (h == 0) {
      const float yt = fmaf(Dc, xc, y);
      const float z = bf2f(*(const unsigned short*)&zbf[basei + (size_t)t * LDI]);
      const float g = z / (1.f + __expf(-z));
      *(unsigned short*)&ygated[basei + (size_t)t * LDI] = f2bf(yt * g);
    }
  }
}

// ---------------------------------------------------------------- launch
extern "C" void kernel_launch(void* const* d_in, const int* in_sizes, int n_in,
                              void* d_out, int out_size, void* d_ws, size_t ws_size,
                              hipStream_t stream) {
  const float* x      = (const float*)d_in[0];
  const float* W_in   = (const float*)d_in[1];
  const float* conv_w = (const float*)d_in[2];
  const float* conv_b = (const float*)d_in[3];
  const float* W_dt   = (const float*)d_in[4];
  const float* b_dt   = (const float*)d_in[5];
  const float* W_B    = (const float*)d_in[6];
  const float* W_C    = (const float*)d_in[7];
  const float* Dvec   = (const float*)d_in[8];
  const float* W_out  = (const float*)d_in[9];
  float* out = (float*)d_out;

  char* p = (char*)d_ws;
  auto alloc = [&](size_t bytes) {
    char* r = p;
    p += (bytes + 255) & ~(size_t)255;
    return r;
  };
  __hip_bfloat16* xin   = (__hip_bfloat16*)alloc((size_t)NTOK * LDI * 2);  // later ygated
  __hip_bfloat16* zbf   = (__hip_bfloat16*)alloc((size_t)NTOK * LDI * 2);
  char*           scr   = alloc((size_t)NTOK * LDH * 2 + (size_t)2 * INNER * LDH * 2);
  __hip_bfloat16* WmidT = (__hip_bfloat16*)alloc((size_t)NMID * LDI * 2);
  __hip_bfloat16* WoutT = (__hip_bfloat16*)alloc((size_t)HID * LDI * 2);
  float*          dtb   = (float*)alloc((size_t)NTOK * LDI * 4);
  float*          Bm    = (float*)alloc((size_t)NTOK * NSTATE * 4);
  float*          Cm    = (float*)alloc((size_t)NTOK * NSTATE * 4);
  float*          Pmid  = (float*)alloc((size_t)2 * NTOK * NMID * 4);
  float*          A_chk = (float*)alloc((size_t)BATCH * NCHUNK * INNER * 4);

  __hip_bfloat16* x_bf   = (__hip_bfloat16*)scr;
  __hip_bfloat16* WinT   = (__hip_bfloat16*)(scr + (size_t)NTOK * LDH * 2);
  __hip_bfloat16* xch    = (__hip_bfloat16*)scr;
  __hip_bfloat16* ygated = xin;
  float*          S      = Pmid;
  float*          Pout   = Pmid;

  // 1. conversions / transposes
  cvt_pad_kernel<<<(NTOK * HID / 4 + 255) / 256, 256, 0, stream>>>(x, x_bf, NTOK * HID / 4);
  transpose_cvt_kernel<<<dim3((2 * INNER) / 32, HID / 32), 256, 0, stream>>>(W_in, WinT, HID, 2 * INNER, LDH);
  transpose_cvt_kernel<<<dim3(INNER / 32, INNER / 32), 256, 0, stream>>>(W_dt, WmidT, INNER, INNER, LDI);
  transpose_cvt_kernel<<<dim3(NSTATE / 32, INNER / 32), 256, 0, stream>>>(
      W_B, WmidT + (size_t)INNER * LDI, INNER, NSTATE, LDI);
  transpose_cvt_kernel<<<dim3(NSTATE / 32, INNER / 32), 256, 0, stream>>>(
      W_C, WmidT + (size_t)(INNER + NSTATE) * LDI, INNER, NSTATE, LDI);
  transpose_cvt_kernel<<<dim3(HID / 32, INNER / 32), 256, 0, stream>>>(W_out, WoutT, INNER, HID, LDI);

  // 2. xz = x @ W_in -> split bf16 (xin | z)   [512 blocks of 256x128]
  {
    const int gridN = (2 * INNER) / 128, nwg = (NTOK / 256) * gridN;
    gemm_bt_kernel<1><<<nwg, 512, 0, stream>>>(
        x_bf, WinT, NTOK, 2 * INNER, HID, LDH, gridN, nwg, nwg, nullptr, 0, LDI, xin, zbf);
  }

  // 3. conv + silu
  conv_silu_kernel<<<(NTOK * (INNER / 4)) / 256, 256, 0, stream>>>(xin, conv_w, conv_b, xch);

  // 4. mid GEMM split-K x2 [544 blocks] + fused reduce/softplus
  {
    const int gridN = NMID / 128;
    const int mnwg = (NTOK / 256) * gridN;      // 272
    const int nwg = mnwg * 2;                   // 544
    gemm_bt_kernel<0><<<nwg, 512, 0, stream>>>(
        xch, WmidT, NTOK, NMID, INNER / 2, LDI, gridN, nwg, mnwg, Pmid, NMID, 0,
        nullptr, nullptr);
    reduce_mid_kernel<<<(NTOK * (NMID / 4)) / 256, 256, 0, stream>>>(Pmid, b_dt, dtb, Bm, Cm);
  }

  // 5. chunked selective scan
  scan_state_kernel<<<dim3(INNER / 128, NCHUNK, BATCH), 256, 0, stream>>>(dtb, xch, Bm, S, A_chk);
  scan_combine_kernel<<<(BATCH * INNER * NSTATE) / 256, 256, 0, stream>>>(S, A_chk);
  scan_out_kernel<<<dim3(INNER / 128, NCHUNK, BATCH), 256, 0, stream>>>(
      dtb, xch, Bm, Cm, S, zbf, Dvec, ygated);

  // 6. out = ygated @ W_out, split-K x4 [512 blocks] + reduce
  {
    const int gridN = HID / 128;
    const int mnwg = (NTOK / 256) * gridN;      // 128
    const int nwg = mnwg * 4;                   // 512
    gemm_bt_kernel<0><<<nwg, 512, 0, stream>>>(
        ygated, WoutT, NTOK, HID, INNER / 4, LDI, gridN, nwg, mnwg, Pout, HID, 0,
        nullptr, nullptr);
    const int n4 = NTOK * HID / 4;
    reduce4_kernel<<<(n4 + 255) / 256, 256, 0, stream>>>(Pout, out, n4);
  }
}

// Round 14
// 340.680 us; speedup vs baseline: 1.1134x; 1.1084x over previous
//
#include <hip/hip_runtime.h>
#include <hip/hip_bf16.h>
#include <math.h>

#define BATCH  2
#define SEQ    2048
#define HID    1024
#define INNER  2048
#define NSTATE 64
#define NTOK   (BATCH * SEQ)
#define TCHUNK 64
#define NCHUNK (SEQ / TCHUNK)
#define NMID   (INNER + 2 * NSTATE)   // 2176
#define LDH    1056
#define LDI    2080

typedef __bf16 bf16x8 __attribute__((ext_vector_type(8)));
typedef float  f32x4  __attribute__((ext_vector_type(4)));

typedef const __attribute__((address_space(1))) char* gas_ptr;
typedef __attribute__((address_space(3))) char*       las_ptr;

__device__ __forceinline__ void gload16(const void* g, void* l) {
  __builtin_amdgcn_global_load_lds((gas_ptr)g, (las_ptr)l, 16, 0, 0);
}

__device__ __forceinline__ unsigned short f2bf(float f) {
  __hip_bfloat16 h = __float2bfloat16(f);
  return __builtin_bit_cast(unsigned short, h);
}
__device__ __forceinline__ float bf2f(unsigned short u) {
  unsigned int x = ((unsigned int)u) << 16;
  return __builtin_bit_cast(float, x);
}

// ---------------------------------------------------------------- cvt fp32->bf16 (padded rows)
__global__ __launch_bounds__(256) void cvt_pad_kernel(
    const float* __restrict__ in, __hip_bfloat16* __restrict__ out, int n4) {
  int i = blockIdx.x * 256 + threadIdx.x;
  if (i >= n4) return;
  const int r = i >> 8;
  const int c = (i & 255) * 4;
  float4 v = *(const float4*)&in[(size_t)r * HID + c];
  ushort4 u;
  u.x = f2bf(v.x); u.y = f2bf(v.y); u.z = f2bf(v.z); u.w = f2bf(v.w);
  *(ushort4*)&out[(size_t)r * LDH + c] = u;
}

// ------------------------------------------------- transpose fp32 [R][C] -> bf16 [C][ostride]
__global__ __launch_bounds__(256) void transpose_cvt_kernel(
    const float* __restrict__ in, __hip_bfloat16* __restrict__ out,
    int R, int C, int ostride) {
  __shared__ float tile[32][33];
  int tx = threadIdx.x & 31, ty = threadIdx.x >> 5;
  int c0 = blockIdx.x * 32, r0 = blockIdx.y * 32;
#pragma unroll
  for (int i = 0; i < 4; ++i)
    tile[ty + 8 * i][tx] = in[(size_t)(r0 + ty + 8 * i) * C + c0 + tx];
  __syncthreads();
#pragma unroll
  for (int i = 0; i < 4; ++i)
    out[(size_t)(c0 + ty + 8 * i) * ostride + r0 + tx] =
        __float2bfloat16(tile[tx][ty + 8 * i]);
}

// ---------------------------------------------------------------- GEMM (r12-proven: 128x128, BK=64)
template <int EPI>
__global__ __launch_bounds__(256, 4) void gemm_bt_kernel(
    const __hip_bfloat16* __restrict__ A, const __hip_bfloat16* __restrict__ Bt,
    int M, int N, int Klen, int ldk, int gridN, int nwg, int mnwg,
    float* __restrict__ Cout, int ldc, int ldo,
    __hip_bfloat16* __restrict__ o0, __hip_bfloat16* __restrict__ o1) {
  __shared__ __align__(16) __hip_bfloat16 As[128 * 64];
  __shared__ __align__(16) __hip_bfloat16 Bs[128 * 64];
  const int tid = threadIdx.x;
  const int lane = tid & 63;
  const int w = tid >> 6;
  const int wr = w >> 1, wc = w & 1;

  const int orig = blockIdx.x;
  const int q8 = nwg >> 3, r8 = nwg & 7;
  const int xcd = orig & 7, seq = orig >> 3;
  const int wg = (xcd < r8 ? xcd * (q8 + 1) : r8 * (q8 + 1) + (xcd - r8) * q8) + seq;
  const int kz = wg / mnwg;
  const int wgr = wg - kz * mnwg;
  const int m0 = (wgr / gridN) * 128;
  const int n0 = (wgr % gridN) * 128;

  const __hip_bfloat16* Ab = A + (size_t)kz * Klen;
  const __hip_bfloat16* Bb = Bt + (size_t)kz * Klen;

  f32x4 acc[4][4];
#pragma unroll
  for (int i = 0; i < 4; ++i)
#pragma unroll
    for (int j = 0; j < 4; ++j)
#pragma unroll
      for (int r2 = 0; r2 < 4; ++r2) acc[i][j][r2] = 0.f;

  const int g8row = lane >> 3;
  const int scol = ((lane & 7) ^ g8row) * 8;
  const __hip_bfloat16* Agp = Ab + (size_t)(m0 + w * 32 + g8row) * ldk + scol;
  const __hip_bfloat16* Bgp = Bb + (size_t)(n0 + w * 32 + g8row) * ldk + scol;
  __hip_bfloat16* lA = As + (w * 32) * 64;
  __hip_bfloat16* lB = Bs + (w * 32) * 64;

  const int lrow = lane & 15, lk = lane >> 4;
  const int arow0 = wr * 64 + lrow;
  const int brow0 = wc * 64 + lrow;

  const int nt = Klen >> 6;
  for (int t = 0; t < nt; ++t) {
    __syncthreads();
#pragma unroll
    for (int g = 0; g < 4; ++g) {
      gload16(Agp + (size_t)(g * 8) * ldk + t * 64, lA + (g * 8) * 64);
      gload16(Bgp + (size_t)(g * 8) * ldk + t * 64, lB + (g * 8) * 64);
    }
    __syncthreads();
#pragma unroll
    for (int ss = 0; ss < 2; ++ss) {
      bf16x8 af[4], bv[4];
#pragma unroll
      for (int i = 0; i < 4; ++i) {
        const int ra = arow0 + i * 16;
        af[i] = *(const bf16x8*)(As + ra * 64 + (((ss * 4 + lk) ^ (ra & 7)) * 8));
        const int rb = brow0 + i * 16;
        bv[i] = *(const bf16x8*)(Bs + rb * 64 + (((ss * 4 + lk) ^ (rb & 7)) * 8));
      }
#pragma unroll
      for (int i = 0; i < 4; ++i)
#pragma unroll
        for (int j = 0; j < 4; ++j)
          acc[i][j] = __builtin_amdgcn_mfma_f32_16x16x32_bf16(af[i], bv[j], acc[i][j], 0, 0, 0);
    }
  }

#pragma unroll
  for (int i = 0; i < 4; ++i) {
#pragma unroll
    for (int j = 0; j < 4; ++j) {
#pragma unroll
      for (int r2 = 0; r2 < 4; ++r2) {
        const int row = m0 + wr * 64 + i * 16 + lk * 4 + r2;
        const int col = n0 + wc * 64 + j * 16 + lrow;
        const float v = acc[i][j][r2];
        if constexpr (EPI == 0) {
          Cout[(size_t)kz * M * ldc + (size_t)row * ldc + col] = v;
        } else {
          if (col < INNER) o0[(size_t)row * ldo + col] = __float2bfloat16(v);
          else             o1[(size_t)row * ldo + (col - INNER)] = __float2bfloat16(v);
        }
      }
    }
  }
}

// ---------------------------------------------------------------- mid reduce: P0+P1 -> packed(dt,xc) | Bm | Cm
__global__ __launch_bounds__(256) void reduce_mid_kernel(
    const float* __restrict__ P, const float* __restrict__ bdt,
    const __hip_bfloat16* __restrict__ xch, unsigned int* __restrict__ dtx,
    float* __restrict__ Bm, float* __restrict__ Cm) {
  const int i = blockIdx.x * 256 + threadIdx.x;
  const int row = i / (NMID / 4);
  const int c4 = i - row * (NMID / 4);
  const int col = c4 * 4;
  const size_t off = (size_t)row * NMID + col;
  float4 a = *(const float4*)&P[off];
  float4 b = *(const float4*)&P[(size_t)NTOK * NMID + off];
  float4 v = make_float4(a.x + b.x, a.y + b.y, a.z + b.z, a.w + b.w);
  if (col < INNER) {
    float4 bb = *(const float4*)&bdt[col];
    float4 d;
    d.x = v.x + bb.x; d.y = v.y + bb.y; d.z = v.z + bb.z; d.w = v.w + bb.w;
    d.x = (d.x > 15.f) ? d.x : log1pf(__expf(d.x));
    d.y = (d.y > 15.f) ? d.y : log1pf(__expf(d.y));
    d.z = (d.z > 15.f) ? d.z : log1pf(__expf(d.z));
    d.w = (d.w > 15.f) ? d.w : log1pf(__expf(d.w));
    ushort4 xv = *(const ushort4*)&xch[(size_t)row * LDI + col];
    uint4 o;
    o.x = (unsigned int)f2bf(d.x) | ((unsigned int)xv.x << 16);
    o.y = (unsigned int)f2bf(d.y) | ((unsigned int)xv.y << 16);
    o.z = (unsigned int)f2bf(d.z) | ((unsigned int)xv.z << 16);
    o.w = (unsigned int)f2bf(d.w) | ((unsigned int)xv.w << 16);
    *(uint4*)&dtx[(size_t)row * LDI + col] = o;
  } else if (col < INNER + NSTATE) {
    *(float4*)&Bm[(size_t)row * NSTATE + (col - INNER)] = v;
  } else {
    *(float4*)&Cm[(size_t)row * NSTATE + (col - INNER - NSTATE)] = v;
  }
}

// ---------------------------------------------------------------- split-K4 reduce (fp32)
__global__ __launch_bounds__(256) void reduce4_kernel(
    const float* __restrict__ P, float* __restrict__ out, int n4) {
  int i = blockIdx.x * 256 + threadIdx.x;
  if (i >= n4) return;
  float4 a = ((const float4*)P)[i];
  float4 b = ((const float4*)P)[i + n4];
  float4 c = ((const float4*)P)[i + 2 * n4];
  float4 d = ((const float4*)P)[i + 3 * n4];
  ((float4*)out)[i] = make_float4((a.x + b.x) + (c.x + d.x), (a.y + b.y) + (c.y + d.y),
                                  (a.z + b.z) + (c.z + d.z), (a.w + b.w) + (c.w + d.w));
}

// ---------------------------------------------------------------- causal depthwise conv + silu
__global__ __launch_bounds__(256) void conv_silu_kernel(
    const __hip_bfloat16* __restrict__ xin, const float* __restrict__ cw,
    const float* __restrict__ cb, __hip_bfloat16* __restrict__ xch) {
  int idx = blockIdx.x * 256 + threadIdx.x;
  int cg = idx & 511;
  int tok = idx >> 9;
  int c = cg * 4;
  int l = tok & (SEQ - 1);
  float wv[4][4];
#pragma unroll
  for (int i = 0; i < 4; ++i) {
    float4 w = *(const float4*)&cw[(c + i) * 4];
    wv[i][0] = w.x; wv[i][1] = w.y; wv[i][2] = w.z; wv[i][3] = w.w;
  }
  float4 bias = *(const float4*)&cb[c];
  float r0 = bias.x, r1 = bias.y, r2 = bias.z, r3 = bias.w;
#pragma unroll
  for (int k = 0; k < 4; ++k) {
    const int d = 3 - k;
    if (l >= d) {
      ushort4 xv = *(const ushort4*)&xin[(size_t)(tok - d) * LDI + c];
      r0 = fmaf(bf2f(xv.x), wv[0][k], r0);
      r1 = fmaf(bf2f(xv.y), wv[1][k], r1);
      r2 = fmaf(bf2f(xv.z), wv[2][k], r2);
      r3 = fmaf(bf2f(xv.w), wv[3][k], r3);
    }
  }
  r0 = r0 / (1.f + __expf(-r0));
  r1 = r1 / (1.f + __expf(-r1));
  r2 = r2 / (1.f + __expf(-r2));
  r3 = r3 / (1.f + __expf(-r3));
  ushort4 u;
  u.x = f2bf(r0); u.y = f2bf(r1); u.z = f2bf(r2); u.w = f2bf(r3);
  *(ushort4*)&xch[(size_t)tok * LDI + c] = u;
}

// ---------------------------------------------------------------- scan phase 1: 2 threads/channel, packed dtx + prefetch
__global__ __launch_bounds__(256, 4) void scan_state_kernel(
    const unsigned int* __restrict__ dtx, const float* __restrict__ Bm,
    float* __restrict__ S, float* __restrict__ A_chunk) {
  __shared__ float Bsh[TCHUNK][64];
  const int b = blockIdx.z, chunk = blockIdx.y;
  const int tid = threadIdx.x;
  const int h = tid & 1;
  const int c = blockIdx.x * 128 + (tid >> 1);
  const int t0 = chunk * TCHUNK;
  for (int i = tid; i < TCHUNK * 16; i += 256) {
    const int row = i >> 4, q = i & 15;
    *(float4*)&Bsh[row][q * 4] =
        *(const float4*)&Bm[((size_t)(b * SEQ + t0 + row)) * NSTATE + q * 4];
  }
  __syncthreads();
  float s[32];
#pragma unroll
  for (int n = 0; n < 32; ++n) s[n] = 0.f;
  float p = 1.f;
  const unsigned int* dx = dtx + (size_t)(b * SEQ + t0) * LDI + c;
  unsigned int cur = dx[0];
#pragma unroll 2
  for (int t = 0; t < TCHUNK; ++t) {
    const unsigned int nxt = dx[(size_t)(t + 1) * LDI];  // prefetch (overread ok, in-ws)
    const float dtv = bf2f((unsigned short)(cur & 0xffffu));
    const float xc = bf2f((unsigned short)(cur >> 16));
    const float at = __expf(-dtv);
    const float ut = dtv * xc;
    p *= at;
    const float* brow = &Bsh[t][h * 32];
#pragma unroll
    for (int q = 0; q < 8; ++q) {
      const float4 bv = *(const float4*)&brow[q * 4];
      s[4 * q + 0] = fmaf(at, s[4 * q + 0], ut * bv.x);
      s[4 * q + 1] = fmaf(at, s[4 * q + 1], ut * bv.y);
      s[4 * q + 2] = fmaf(at, s[4 * q + 2], ut * bv.z);
      s[4 * q + 3] = fmaf(at, s[4 * q + 3], ut * bv.w);
    }
    cur = nxt;
  }
  const size_t sbase = ((size_t)(b * NCHUNK + chunk) * INNER + c) * NSTATE + h * 32;
#pragma unroll
  for (int q = 0; q < 8; ++q)
    *(float4*)&S[sbase + 4 * q] =
        make_float4(s[4 * q], s[4 * q + 1], s[4 * q + 2], s[4 * q + 3]);
  if (h == 0) A_chunk[(size_t)(b * NCHUNK + chunk) * INNER + c] = p;
}

// ---------------------------------------------------------------- scan phase 2 (in place)
__global__ __launch_bounds__(256) void scan_combine_kernel(
    float* __restrict__ S, const float* __restrict__ A_chunk) {
  const int idx = blockIdx.x * 256 + threadIdx.x;
  const int n = idx & 63;
  const int c = (idx >> 6) & (INNER - 1);
  const int b = idx >> 17;
  float s = 0.f;
  for (int k = 0; k < NCHUNK; ++k) {
    const size_t cs = (size_t)(b * NCHUNK + k) * INNER + c;
    const size_t off = cs * NSTATE + n;
    const float loc = S[off];
    S[off] = s;
    s = fmaf(A_chunk[cs], s, loc);
  }
}

// ---------------------------------------------------------------- scan phase 3: packed dtx + prefetch
__global__ __launch_bounds__(256, 4) void scan_out_kernel(
    const unsigned int* __restrict__ dtx,
    const float* __restrict__ Bm, const float* __restrict__ Cm,
    const float* __restrict__ S_in, const __hip_bfloat16* __restrict__ zbf,
    const float* __restrict__ Dv, __hip_bfloat16* __restrict__ ygated) {
  __shared__ float Bsh[TCHUNK][64];
  __shared__ float Csh[TCHUNK][64];
  const int b = blockIdx.z, chunk = blockIdx.y;
  const int tid = threadIdx.x;
  const int h = tid & 1;
  const int c = blockIdx.x * 128 + (tid >> 1);
  const int t0 = chunk * TCHUNK;
  for (int i = tid; i < TCHUNK * 16; i += 256) {
    const int row = i >> 4, q = i & 15;
    const size_t src = ((size_t)(b * SEQ + t0 + row)) * NSTATE + q * 4;
    *(float4*)&Bsh[row][q * 4] = *(const float4*)&Bm[src];
    *(float4*)&Csh[row][q * 4] = *(const float4*)&Cm[src];
  }
  __syncthreads();
  float s[32];
  const size_t sbase = ((size_t)(b * NCHUNK + chunk) * INNER + c) * NSTATE + h * 32;
#pragma unroll
  for (int q = 0; q < 8; ++q) {
    const float4 v = *(const float4*)&S_in[sbase + 4 * q];
    s[4 * q] = v.x; s[4 * q + 1] = v.y; s[4 * q + 2] = v.z; s[4 * q + 3] = v.w;
  }
  const float Dc = Dv[c];
  const size_t basei = (size_t)(b * SEQ + t0) * LDI + c;
  const unsigned int* dx = dtx + basei;
  const unsigned short* zp = (const unsigned short*)zbf + basei;
  unsigned int cur = dx[0];
  unsigned short zc = zp[0];
#pragma unroll 2
  for (int t = 0; t < TCHUNK; ++t) {
    const unsigned int nxt = dx[(size_t)(t + 1) * LDI];   // prefetch (overread ok)
    const unsigned short zn = zp[(size_t)(t + 1) * LDI];
    const float dtv = bf2f((unsigned short)(cur & 0xffffu));
    const float xc = bf2f((unsigned short)(cur >> 16));
    const float at = __expf(-dtv);
    const float ut = dtv * xc;
    const float* brow = &Bsh[t][h * 32];
    const float* crow = &Csh[t][h * 32];
    float y0 = 0.f, y1 = 0.f, y2 = 0.f, y3 = 0.f;
#pragma unroll
    for (int q = 0; q < 8; ++q) {
      const float4 bv = *(const float4*)&brow[q * 4];
      const float4 cv = *(const float4*)&crow[q * 4];
      s[4 * q + 0] = fmaf(at, s[4 * q + 0], ut * bv.x);
      s[4 * q + 1] = fmaf(at, s[4 * q + 1], ut * bv.y);
      s[4 * q + 2] = fmaf(at, s[4 * q + 2], ut * bv.z);
      s[4 * q + 3] = fmaf(at, s[4 * q + 3], ut * bv.w);
      y0 = fmaf(s[4 * q + 0], cv.x, y0);
      y1 = fmaf(s[4 * q + 1], cv.y, y1);
      y2 = fmaf(s[4 * q + 2], cv.z, y2);
      y3 = fmaf(s[4 * q + 3], cv.w, y3);
    }
    float y = (y0 + y1) + (y2 + y3);
    y += __shfl_xor(y, 1);
    if (h == 0) {
      const float yt = fmaf(Dc, xc, y);
      const float z = bf2f(zc);
      const float g = z / (1.f + __expf(-z));
      *(unsigned short*)&ygated[basei + (size_t)t * LDI] = f2bf(yt * g);
    }
    cur = nxt;
    zc = zn;
  }
}

// ---------------------------------------------------------------- launch
extern "C" void kernel_launch(void* const* d_in, const int* in_sizes, int n_in,
                              void* d_out, int out_size, void* d_ws, size_t ws_size,
                              hipStream_t stream) {
  const float* x      = (const float*)d_in[0];
  const float* W_in   = (const float*)d_in[1];
  const float* conv_w = (const float*)d_in[2];
  const float* conv_b = (const float*)d_in[3];
  const float* W_dt   = (const float*)d_in[4];
  const float* b_dt   = (const float*)d_in[5];
  const float* W_B    = (const float*)d_in[6];
  const float* W_C    = (const float*)d_in[7];
  const float* Dvec   = (const float*)d_in[8];
  const float* W_out  = (const float*)d_in[9];
  float* out = (float*)d_out;

  char* p = (char*)d_ws;
  auto alloc = [&](size_t bytes) {
    char* r = p;
    p += (bytes + 255) & ~(size_t)255;
    return r;
  };
  __hip_bfloat16* xin   = (__hip_bfloat16*)alloc((size_t)NTOK * LDI * 2);  // later ygated
  __hip_bfloat16* zbf   = (__hip_bfloat16*)alloc((size_t)NTOK * LDI * 2);
  char*           scr   = alloc((size_t)NTOK * LDH * 2 + (size_t)2 * INNER * LDH * 2);
  __hip_bfloat16* WmidT = (__hip_bfloat16*)alloc((size_t)NMID * LDI * 2);
  __hip_bfloat16* WoutT = (__hip_bfloat16*)alloc((size_t)HID * LDI * 2);
  unsigned int*   dtx   = (unsigned int*)alloc((size_t)NTOK * LDI * 4);
  float*          Bm    = (float*)alloc((size_t)NTOK * NSTATE * 4);
  float*          Cm    = (float*)alloc((size_t)NTOK * NSTATE * 4);
  float*          Pmid  = (float*)alloc((size_t)2 * NTOK * NMID * 4);
  float*          A_chk = (float*)alloc((size_t)BATCH * NCHUNK * INNER * 4);

  __hip_bfloat16* x_bf   = (__hip_bfloat16*)scr;
  __hip_bfloat16* WinT   = (__hip_bfloat16*)(scr + (size_t)NTOK * LDH * 2);
  __hip_bfloat16* xch    = (__hip_bfloat16*)scr;
  __hip_bfloat16* ygated = xin;
  float*          S      = Pmid;
  float*          Pout   = Pmid;

  // 1. conversions / transposes
  cvt_pad_kernel<<<(NTOK * HID / 4 + 255) / 256, 256, 0, stream>>>(x, x_bf, NTOK * HID / 4);
  transpose_cvt_kernel<<<dim3((2 * INNER) / 32, HID / 32), 256, 0, stream>>>(W_in, WinT, HID, 2 * INNER, LDH);
  transpose_cvt_kernel<<<dim3(INNER / 32, INNER / 32), 256, 0, stream>>>(W_dt, WmidT, INNER, INNER, LDI);
  transpose_cvt_kernel<<<dim3(NSTATE / 32, INNER / 32), 256, 0, stream>>>(
      W_B, WmidT + (size_t)INNER * LDI, INNER, NSTATE, LDI);
  transpose_cvt_kernel<<<dim3(NSTATE / 32, INNER / 32), 256, 0, stream>>>(
      W_C, WmidT + (size_t)(INNER + NSTATE) * LDI, INNER, NSTATE, LDI);
  transpose_cvt_kernel<<<dim3(HID / 32, INNER / 32), 256, 0, stream>>>(W_out, WoutT, INNER, HID, LDI);

  // 2. xz = x @ W_in -> split bf16 (xin | z)  [1024 blocks, 4/CU]
  {
    const int gridN = (2 * INNER) / 128, nwg = (NTOK / 128) * gridN;
    gemm_bt_kernel<1><<<nwg, 256, 0, stream>>>(
        x_bf, WinT, NTOK, 2 * INNER, HID, LDH, gridN, nwg, nwg, nullptr, 0, LDI, xin, zbf);
  }

  // 3. conv + silu
  conv_silu_kernel<<<(NTOK * (INNER / 4)) / 256, 256, 0, stream>>>(xin, conv_w, conv_b, xch);

  // 4. mid GEMM split-K x2 [1088 blocks, 4.25/CU] + fused reduce/softplus/pack
  {
    const int gridN = NMID / 128;
    const int mnwg = (NTOK / 128) * gridN;
    const int nwg = mnwg * 2;
    gemm_bt_kernel<0><<<nwg, 256, 0, stream>>>(
        xch, WmidT, NTOK, NMID, INNER / 2, LDI, gridN, nwg, mnwg, Pmid, NMID, 0,
        nullptr, nullptr);
    reduce_mid_kernel<<<(NTOK * (NMID / 4)) / 256, 256, 0, stream>>>(Pmid, b_dt, xch, dtx, Bm, Cm);
  }

  // 5. chunked selective scan (packed dtx, prefetched)
  scan_state_kernel<<<dim3(INNER / 128, NCHUNK, BATCH), 256, 0, stream>>>(dtx, Bm, S, A_chk);
  scan_combine_kernel<<<(BATCH * INNER * NSTATE) / 256, 256, 0, stream>>>(S, A_chk);
  scan_out_kernel<<<dim3(INNER / 128, NCHUNK, BATCH), 256, 0, stream>>>(
      dtx, Bm, Cm, S, zbf, Dvec, ygated);

  // 6. out = ygated @ W_out, split-K x4 [1024 blocks, 4/CU] + reduce
  {
    const int gridN = HID / 128;
    const int mnwg = (NTOK / 128) * gridN;
    const int nwg = mnwg * 4;
    gemm_bt_kernel<0><<<nwg, 256, 0, stream>>>(
        ygated, WoutT, NTOK, HID, INNER / 4, LDI, gridN, nwg, mnwg, Pout, HID, 0,
        nullptr, nullptr);
    const int n4 = NTOK * HID / 4;
    reduce4_kernel<<<(n4 + 255) / 256, 256, 0, stream>>>(Pout, out, n4);
  }
}

// Round 15
// 327.729 us; speedup vs baseline: 1.1574x; 1.0395x over previous
//
#include <hip/hip_runtime.h>
#include <hip/hip_bf16.h>
#include <math.h>

#define BATCH  2
#define SEQ    2048
#define HID    1024
#define INNER  2048
#define NSTATE 64
#define NTOK   (BATCH * SEQ)
#define TCHUNK 64
#define NCHUNK (SEQ / TCHUNK)
#define NMID   (INNER + 2 * NSTATE)   // 2176
#define LDH    1056
#define LDI    2080

typedef __bf16 bf16x8 __attribute__((ext_vector_type(8)));
typedef float  f32x4  __attribute__((ext_vector_type(4)));

typedef const __attribute__((address_space(1))) char* gas_ptr;
typedef __attribute__((address_space(3))) char*       las_ptr;

__device__ __forceinline__ void gload16(const void* g, void* l) {
  __builtin_amdgcn_global_load_lds((gas_ptr)g, (las_ptr)l, 16, 0, 0);
}

__device__ __forceinline__ unsigned short f2bf(float f) {
  __hip_bfloat16 h = __float2bfloat16(f);
  return __builtin_bit_cast(unsigned short, h);
}
__device__ __forceinline__ float bf2f(unsigned short u) {
  unsigned int x = ((unsigned int)u) << 16;
  return __builtin_bit_cast(float, x);
}

// ---------------------------------------------------------------- cvt fp32->bf16 (padded rows)
__global__ __launch_bounds__(256) void cvt_pad_kernel(
    const float* __restrict__ in, __hip_bfloat16* __restrict__ out, int n4) {
  int i = blockIdx.x * 256 + threadIdx.x;
  if (i >= n4) return;
  const int r = i >> 8;
  const int c = (i & 255) * 4;
  float4 v = *(const float4*)&in[(size_t)r * HID + c];
  ushort4 u;
  u.x = f2bf(v.x); u.y = f2bf(v.y); u.z = f2bf(v.z); u.w = f2bf(v.w);
  *(ushort4*)&out[(size_t)r * LDH + c] = u;
}

// ------------------------------------------------- transpose fp32 [R][C] -> bf16 [C][ostride]
__global__ __launch_bounds__(256) void transpose_cvt_kernel(
    const float* __restrict__ in, __hip_bfloat16* __restrict__ out,
    int R, int C, int ostride) {
  __shared__ float tile[32][33];
  int tx = threadIdx.x & 31, ty = threadIdx.x >> 5;
  int c0 = blockIdx.x * 32, r0 = blockIdx.y * 32;
#pragma unroll
  for (int i = 0; i < 4; ++i)
    tile[ty + 8 * i][tx] = in[(size_t)(r0 + ty + 8 * i) * C + c0 + tx];
  __syncthreads();
#pragma unroll
  for (int i = 0; i < 4; ++i)
    out[(size_t)(c0 + ty + 8 * i) * ostride + r0 + tx] =
        __float2bfloat16(tile[tx][ty + 8 * i]);
}

// ---------------------------------------------------------------- GEMM (r12-proven: 128x128, BK=64)
template <int EPI>
__global__ __launch_bounds__(256, 4) void gemm_bt_kernel(
    const __hip_bfloat16* __restrict__ A, const __hip_bfloat16* __restrict__ Bt,
    int M, int N, int Klen, int ldk, int gridN, int nwg, int mnwg,
    float* __restrict__ Cout, int ldc, int ldo,
    __hip_bfloat16* __restrict__ o0, __hip_bfloat16* __restrict__ o1) {
  __shared__ __align__(16) __hip_bfloat16 As[128 * 64];
  __shared__ __align__(16) __hip_bfloat16 Bs[128 * 64];
  const int tid = threadIdx.x;
  const int lane = tid & 63;
  const int w = tid >> 6;
  const int wr = w >> 1, wc = w & 1;

  const int orig = blockIdx.x;
  const int q8 = nwg >> 3, r8 = nwg & 7;
  const int xcd = orig & 7, seq = orig >> 3;
  const int wg = (xcd < r8 ? xcd * (q8 + 1) : r8 * (q8 + 1) + (xcd - r8) * q8) + seq;
  const int kz = wg / mnwg;
  const int wgr = wg - kz * mnwg;
  const int m0 = (wgr / gridN) * 128;
  const int n0 = (wgr % gridN) * 128;

  const __hip_bfloat16* Ab = A + (size_t)kz * Klen;
  const __hip_bfloat16* Bb = Bt + (size_t)kz * Klen;

  f32x4 acc[4][4];
#pragma unroll
  for (int i = 0; i < 4; ++i)
#pragma unroll
    for (int j = 0; j < 4; ++j)
#pragma unroll
      for (int r2 = 0; r2 < 4; ++r2) acc[i][j][r2] = 0.f;

  const int g8row = lane >> 3;
  const int scol = ((lane & 7) ^ g8row) * 8;
  const __hip_bfloat16* Agp = Ab + (size_t)(m0 + w * 32 + g8row) * ldk + scol;
  const __hip_bfloat16* Bgp = Bb + (size_t)(n0 + w * 32 + g8row) * ldk + scol;
  __hip_bfloat16* lA = As + (w * 32) * 64;
  __hip_bfloat16* lB = Bs + (w * 32) * 64;

  const int lrow = lane & 15, lk = lane >> 4;
  const int arow0 = wr * 64 + lrow;
  const int brow0 = wc * 64 + lrow;

  const int nt = Klen >> 6;
  for (int t = 0; t < nt; ++t) {
    __syncthreads();
#pragma unroll
    for (int g = 0; g < 4; ++g) {
      gload16(Agp + (size_t)(g * 8) * ldk + t * 64, lA + (g * 8) * 64);
      gload16(Bgp + (size_t)(g * 8) * ldk + t * 64, lB + (g * 8) * 64);
    }
    __syncthreads();
#pragma unroll
    for (int ss = 0; ss < 2; ++ss) {
      bf16x8 af[4], bv[4];
#pragma unroll
      for (int i = 0; i < 4; ++i) {
        const int ra = arow0 + i * 16;
        af[i] = *(const bf16x8*)(As + ra * 64 + (((ss * 4 + lk) ^ (ra & 7)) * 8));
        const int rb = brow0 + i * 16;
        bv[i] = *(const bf16x8*)(Bs + rb * 64 + (((ss * 4 + lk) ^ (rb & 7)) * 8));
      }
#pragma unroll
      for (int i = 0; i < 4; ++i)
#pragma unroll
        for (int j = 0; j < 4; ++j)
          acc[i][j] = __builtin_amdgcn_mfma_f32_16x16x32_bf16(af[i], bv[j], acc[i][j], 0, 0, 0);
    }
  }

#pragma unroll
  for (int i = 0; i < 4; ++i) {
#pragma unroll
    for (int j = 0; j < 4; ++j) {
#pragma unroll
      for (int r2 = 0; r2 < 4; ++r2) {
        const int row = m0 + wr * 64 + i * 16 + lk * 4 + r2;
        const int col = n0 + wc * 64 + j * 16 + lrow;
        const float v = acc[i][j][r2];
        if constexpr (EPI == 0) {
          Cout[(size_t)kz * M * ldc + (size_t)row * ldc + col] = v;
        } else {
          if (col < INNER) o0[(size_t)row * ldo + col] = __float2bfloat16(v);
          else             o1[(size_t)row * ldo + (col - INNER)] = __float2bfloat16(v);
        }
      }
    }
  }
}

// ---------------------------------------------------------------- mid reduce: P0+P1 -> packed(dt,xc) | Bm | Cm
__global__ __launch_bounds__(256) void reduce_mid_kernel(
    const float* __restrict__ P, const float* __restrict__ bdt,
    const __hip_bfloat16* __restrict__ xch, unsigned int* __restrict__ dtx,
    float* __restrict__ Bm, float* __restrict__ Cm) {
  const int i = blockIdx.x * 256 + threadIdx.x;
  const int row = i / (NMID / 4);
  const int c4 = i - row * (NMID / 4);
  const int col = c4 * 4;
  const size_t off = (size_t)row * NMID + col;
  float4 a = *(const float4*)&P[off];
  float4 b = *(const float4*)&P[(size_t)NTOK * NMID + off];
  float4 v = make_float4(a.x + b.x, a.y + b.y, a.z + b.z, a.w + b.w);
  if (col < INNER) {
    float4 bb = *(const float4*)&bdt[col];
    float4 d;
    d.x = v.x + bb.x; d.y = v.y + bb.y; d.z = v.z + bb.z; d.w = v.w + bb.w;
    d.x = (d.x > 15.f) ? d.x : log1pf(__expf(d.x));
    d.y = (d.y > 15.f) ? d.y : log1pf(__expf(d.y));
    d.z = (d.z > 15.f) ? d.z : log1pf(__expf(d.z));
    d.w = (d.w > 15.f) ? d.w : log1pf(__expf(d.w));
    ushort4 xv = *(const ushort4*)&xch[(size_t)row * LDI + col];
    uint4 o;
    o.x = (unsigned int)f2bf(d.x) | ((unsigned int)xv.x << 16);
    o.y = (unsigned int)f2bf(d.y) | ((unsigned int)xv.y << 16);
    o.z = (unsigned int)f2bf(d.z) | ((unsigned int)xv.z << 16);
    o.w = (unsigned int)f2bf(d.w) | ((unsigned int)xv.w << 16);
    *(uint4*)&dtx[(size_t)row * LDI + col] = o;
  } else if (col < INNER + NSTATE) {
    *(float4*)&Bm[(size_t)row * NSTATE + (col - INNER)] = v;
  } else {
    *(float4*)&Cm[(size_t)row * NSTATE + (col - INNER - NSTATE)] = v;
  }
}

// ---------------------------------------------------------------- split-K4 reduce (fp32)
__global__ __launch_bounds__(256) void reduce4_kernel(
    const float* __restrict__ P, float* __restrict__ out, int n4) {
  int i = blockIdx.x * 256 + threadIdx.x;
  if (i >= n4) return;
  float4 a = ((const float4*)P)[i];
  float4 b = ((const float4*)P)[i + n4];
  float4 c = ((const float4*)P)[i + 2 * n4];
  float4 d = ((const float4*)P)[i + 3 * n4];
  ((float4*)out)[i] = make_float4((a.x + b.x) + (c.x + d.x), (a.y + b.y) + (c.y + d.y),
                                  (a.z + b.z) + (c.z + d.z), (a.w + b.w) + (c.w + d.w));
}

// ---------------------------------------------------------------- causal depthwise conv + silu
__global__ __launch_bounds__(256) void conv_silu_kernel(
    const __hip_bfloat16* __restrict__ xin, const float* __restrict__ cw,
    const float* __restrict__ cb, __hip_bfloat16* __restrict__ xch) {
  int idx = blockIdx.x * 256 + threadIdx.x;
  int cg = idx & 511;
  int tok = idx >> 9;
  int c = cg * 4;
  int l = tok & (SEQ - 1);
  float wv[4][4];
#pragma unroll
  for (int i = 0; i < 4; ++i) {
    float4 w = *(const float4*)&cw[(c + i) * 4];
    wv[i][0] = w.x; wv[i][1] = w.y; wv[i][2] = w.z; wv[i][3] = w.w;
  }
  float4 bias = *(const float4*)&cb[c];
  float r0 = bias.x, r1 = bias.y, r2 = bias.z, r3 = bias.w;
#pragma unroll
  for (int k = 0; k < 4; ++k) {
    const int d = 3 - k;
    if (l >= d) {
      ushort4 xv = *(const ushort4*)&xin[(size_t)(tok - d) * LDI + c];
      r0 = fmaf(bf2f(xv.x), wv[0][k], r0);
      r1 = fmaf(bf2f(xv.y), wv[1][k], r1);
      r2 = fmaf(bf2f(xv.z), wv[2][k], r2);
      r3 = fmaf(bf2f(xv.w), wv[3][k], r3);
    }
  }
  r0 = r0 / (1.f + __expf(-r0));
  r1 = r1 / (1.f + __expf(-r1));
  r2 = r2 / (1.f + __expf(-r2));
  r3 = r3 / (1.f + __expf(-r3));
  ushort4 u;
  u.x = f2bf(r0); u.y = f2bf(r1); u.z = f2bf(r2); u.w = f2bf(r3);
  *(ushort4*)&xch[(size_t)tok * LDI + c] = u;
}

// ---------------------------------------------------------------- cumA + w (chunked decay factors)
// cumA[tok][c] = prod_{j<=t} exp(-dt)  (f32, stride INNER)
// wT[bk][c][tau] = bf16( dt*xc / cumA )  (tau-contiguous per channel)
__global__ __launch_bounds__(256) void cumv_kernel(
    const unsigned int* __restrict__ dtx, float* __restrict__ cumA,
    unsigned int* __restrict__ wT) {
  const int bk = blockIdx.y;
  const int c = blockIdx.x * 256 + threadIdx.x;
  const int b = bk >> 5, k = bk & 31;
  const size_t tokbase = (size_t)(b * SEQ + k * TCHUNK);
  float cum = 1.f;
  unsigned int wreg[32];
#pragma unroll
  for (int t = 0; t < TCHUNK; ++t) {
    const unsigned int pk = dtx[(tokbase + t) * LDI + c];
    const float dtv = bf2f((unsigned short)(pk & 0xffffu));
    const float xc = bf2f((unsigned short)(pk >> 16));
    cum *= __expf(-dtv);
    cum = fmaxf(cum, 1e-30f);
    cumA[(tokbase + t) * INNER + c] = cum;
    const unsigned short wb = f2bf(dtv * xc / cum);
    if (t & 1) wreg[t >> 1] |= ((unsigned int)wb) << 16;
    else       wreg[t >> 1] = (unsigned int)wb;
  }
  uint4* dst = (uint4*)(wT + ((size_t)bk * INNER + c) * 32);
#pragma unroll
  for (int j = 0; j < 8; ++j)
    dst[j] = make_uint4(wreg[4 * j], wreg[4 * j + 1], wreg[4 * j + 2], wreg[4 * j + 3]);
}

// ---------------------------------------------------------------- per-chunk G = tril(C@B^T), + bf16 C / B^T copies
// Abuf[bk][t][0..63] = tril G bf16; Abuf[bk][t][64..127] = C[t][n] bf16.
// BtBuf[bk][n][tau] = B[tau][n] bf16.
__global__ __launch_bounds__(256) void chunkG_kernel(
    const float* __restrict__ Bm, const float* __restrict__ Cm,
    __hip_bfloat16* __restrict__ Abuf, __hip_bfloat16* __restrict__ BtBuf) {
  __shared__ float Bsh[TCHUNK][NSTATE + 4];
  __shared__ float Csh[TCHUNK][NSTATE + 4];
  const int bk = blockIdx.x;
  const int b = bk >> 5, k = bk & 31;
  const int tid = threadIdx.x;
  const size_t tokbase = (size_t)(b * SEQ + k * TCHUNK);
  for (int i = tid; i < TCHUNK * 16; i += 256) {
    const int row = i >> 4, q = i & 15;
    *(float4*)&Bsh[row][q * 4] = *(const float4*)&Bm[(tokbase + row) * NSTATE + q * 4];
    *(float4*)&Csh[row][q * 4] = *(const float4*)&Cm[(tokbase + row) * NSTATE + q * 4];
  }
  __syncthreads();
  for (int e = tid; e < 64 * 64; e += 256) {
    const int t = e >> 6, tau = e & 63;
    float g = 0.f;
    if (tau <= t) {
#pragma unroll
      for (int q = 0; q < 16; ++q) {
        const float4 cv = *(const float4*)&Csh[t][q * 4];
        const float4 bv = *(const float4*)&Bsh[tau][q * 4];
        g += cv.x * bv.x + cv.y * bv.y + cv.z * bv.z + cv.w * bv.w;
      }
    }
    Abuf[((size_t)bk * 64 + t) * 128 + tau] = __float2bfloat16(g);
  }
  for (int e = tid; e < 64 * 64; e += 256) {
    const int n2 = e >> 6, r = e & 63;   // coalesced over r
    BtBuf[((size_t)bk * 64 + n2) * 64 + r] = __float2bfloat16(Bsh[r][n2]);
    Abuf[((size_t)bk * 64 + n2) * 128 + 64 + r] = __float2bfloat16(Csh[n2][r]);
  }
}

// ---------------------------------------------------------------- S_loc GEMM: S[bk][c][n] = cumA_T[c] * (wT @ BtBuf^T)
__global__ __launch_bounds__(256, 4) void sloc_gemm_kernel(
    const __hip_bfloat16* __restrict__ wT, const __hip_bfloat16* __restrict__ BtBuf,
    const float* __restrict__ cumA, float* __restrict__ S) {
  __shared__ __align__(16) __hip_bfloat16 As[128 * 64];
  __shared__ __align__(16) __hip_bfloat16 Bs[64 * 64];
  const int tid = threadIdx.x;
  const int lane = tid & 63;
  const int w = tid >> 6;
  const int bk = blockIdx.x >> 4;
  const int ct = blockIdx.x & 15;
  const int b = bk >> 5, k = bk & 31;
  const int c0 = ct * 128;

  const int g8row = lane >> 3;
  const int scol = ((lane & 7) ^ g8row) * 8;
  const __hip_bfloat16* Ag = wT + ((size_t)bk * INNER + c0 + w * 32 + g8row) * 64 + scol;
  const __hip_bfloat16* Bg = BtBuf + ((size_t)bk * 64 + w * 16 + g8row) * 64 + scol;
  __hip_bfloat16* lA = As + (w * 32) * 64;
  __hip_bfloat16* lB = Bs + (w * 16) * 64;
#pragma unroll
  for (int g = 0; g < 4; ++g) gload16(Ag + (size_t)(g * 8) * 64, lA + (g * 8) * 64);
#pragma unroll
  for (int g = 0; g < 2; ++g) gload16(Bg + (size_t)(g * 8) * 64, lB + (g * 8) * 64);
  __syncthreads();

  const int lrow = lane & 15, lk = lane >> 4;
  f32x4 acc[2][4];
#pragma unroll
  for (int i = 0; i < 2; ++i)
#pragma unroll
    for (int j = 0; j < 4; ++j)
#pragma unroll
      for (int r2 = 0; r2 < 4; ++r2) acc[i][j][r2] = 0.f;

#pragma unroll
  for (int ss = 0; ss < 2; ++ss) {
    bf16x8 af[2], bv[4];
#pragma unroll
    for (int i = 0; i < 2; ++i) {
      const int ra = w * 32 + i * 16 + lrow;
      af[i] = *(const bf16x8*)(As + ra * 64 + (((ss * 4 + lk) ^ (ra & 7)) * 8));
    }
#pragma unroll
    for (int j = 0; j < 4; ++j) {
      const int rb = j * 16 + lrow;
      bv[j] = *(const bf16x8*)(Bs + rb * 64 + (((ss * 4 + lk) ^ (rb & 7)) * 8));
    }
#pragma unroll
    for (int i = 0; i < 2; ++i)
#pragma unroll
      for (int j = 0; j < 4; ++j)
        acc[i][j] = __builtin_amdgcn_mfma_f32_16x16x32_bf16(af[i], bv[j], acc[i][j], 0, 0, 0);
  }

  const size_t tokT = (size_t)(b * SEQ + k * TCHUNK + 63);
#pragma unroll
  for (int i = 0; i < 2; ++i) {
#pragma unroll
    for (int j = 0; j < 4; ++j) {
#pragma unroll
      for (int r2 = 0; r2 < 4; ++r2) {
        const int c = c0 + w * 32 + i * 16 + lk * 4 + r2;
        const int n = j * 16 + lrow;
        const float sc = cumA[tokT * INNER + c];
        S[((size_t)bk * INNER + c) * 64 + n] = acc[i][j][r2] * sc;
      }
    }
  }
}

// ---------------------------------------------------------------- cross-chunk combine (in place; A from cumA)
__global__ __launch_bounds__(256) void scan_combine_kernel(
    float* __restrict__ S, const float* __restrict__ cumA) {
  const int idx = blockIdx.x * 256 + threadIdx.x;
  const int n = idx & 63;
  const int c = (idx >> 6) & (INNER - 1);
  const int b = idx >> 17;
  float s = 0.f;
  for (int k = 0; k < NCHUNK; ++k) {
    const size_t cs = (size_t)(b * NCHUNK + k) * INNER + c;
    const size_t off = cs * 64 + n;
    const float loc = S[off];
    S[off] = s;
    const float ak = cumA[((size_t)(b * SEQ + k * TCHUNK + 63)) * INNER + c];
    s = fmaf(ak, s, loc);
  }
}

// ---------------------------------------------------------------- y GEMM: [trilG|C] @ [wT;S_in] -> epilogue
__global__ __launch_bounds__(256, 4) void ypre_gemm_kernel(
    const __hip_bfloat16* __restrict__ Abuf, const __hip_bfloat16* __restrict__ wT,
    const float* __restrict__ S, const float* __restrict__ cumA,
    const __hip_bfloat16* __restrict__ xch, const __hip_bfloat16* __restrict__ zbf,
    const float* __restrict__ Dv, __hip_bfloat16* __restrict__ ygated) {
  __shared__ __align__(16) __hip_bfloat16 Asm[64 * 128];   // [t][k]
  __shared__ __align__(16) __hip_bfloat16 Bsm[128 * 128];  // [c][k]
  const int tid = threadIdx.x;
  const int lane = tid & 63;
  const int w = tid >> 6;
  const int bk = blockIdx.x >> 4;
  const int ct = blockIdx.x & 15;
  const int b = bk >> 5, k = bk & 31;
  const int c0 = ct * 128;

  // stage A (Abuf rows, 256B each) via gload16: 4 rows/load, swizzled source
  {
#pragma unroll
    for (int g = 0; g < 4; ++g) {
      const int base = w * 16 + g * 4;
      const int col16s = (lane & 15) ^ ((base + (lane >> 4)) & 7);
      const __hip_bfloat16* src =
          Abuf + ((size_t)bk * 64 + base + (lane >> 4)) * 128 + col16s * 8;
      gload16(src, (char*)Asm + base * 256);
    }
  }
  // stage B: row = tid&127 (c), part 0 = wT half (slots 0..7), part 1 = S_in bf16 (slots 8..15)
  {
    const int row = tid & 127, part = tid >> 7;
    const int c = c0 + row;
    if (part == 0) {
      const uint4* src = (const uint4*)(wT + ((size_t)bk * INNER + c) * 64);
#pragma unroll
      for (int s2 = 0; s2 < 8; ++s2) {
        uint4 v = src[s2];
        *(uint4*)((char*)Bsm + row * 256 + (s2 ^ (row & 7)) * 16) = v;
      }
    } else {
      const float* srcS = S + ((size_t)bk * INNER + c) * 64;
#pragma unroll
      for (int s2 = 0; s2 < 8; ++s2) {
        float4 a2 = *(const float4*)&srcS[s2 * 8];
        float4 b2 = *(const float4*)&srcS[s2 * 8 + 4];
        uint4 v;
        v.x = (unsigned)f2bf(a2.x) | ((unsigned)f2bf(a2.y) << 16);
        v.y = (unsigned)f2bf(a2.z) | ((unsigned)f2bf(a2.w) << 16);
        v.z = (unsigned)f2bf(b2.x) | ((unsigned)f2bf(b2.y) << 16);
        v.w = (unsigned)f2bf(b2.z) | ((unsigned)f2bf(b2.w) << 16);
        *(uint4*)((char*)Bsm + row * 256 + ((8 + s2) ^ (row & 7)) * 16) = v;
      }
    }
  }
  __syncthreads();

  const int lrow = lane & 15, lk = lane >> 4;
  f32x4 acc[8];
#pragma unroll
  for (int j = 0; j < 8; ++j)
#pragma unroll
    for (int r2 = 0; r2 < 4; ++r2) acc[j][r2] = 0.f;

  const int ra = w * 16 + lrow;
#pragma unroll
  for (int kk = 0; kk < 4; ++kk) {
    const int csa = (kk * 4 + lk) ^ (ra & 7);
    bf16x8 af = *(const bf16x8*)((const char*)Asm + ra * 256 + csa * 16);
#pragma unroll
    for (int j = 0; j < 8; ++j) {
      const int rb = j * 16 + lrow;
      const int csb = (kk * 4 + lk) ^ (rb & 7);
      bf16x8 bv = *(const bf16x8*)((const char*)Bsm + rb * 256 + csb * 16);
      acc[j] = __builtin_amdgcn_mfma_f32_16x16x32_bf16(af, bv, acc[j], 0, 0, 0);
    }
  }

  const size_t tokb = (size_t)(b * SEQ + k * TCHUNK);
#pragma unroll
  for (int j = 0; j < 8; ++j) {
#pragma unroll
    for (int r2 = 0; r2 < 4; ++r2) {
      const int t = w * 16 + lk * 4 + r2;
      const int c = c0 + j * 16 + lrow;
      const size_t tok = tokb + t;
      const float ca = cumA[tok * INNER + c];
      const float xc = bf2f(*(const unsigned short*)&xch[tok * LDI + c]);
      const float z = bf2f(*(const unsigned short*)&zbf[tok * LDI + c]);
      const float yt = ca * acc[j][r2] + Dv[c] * xc;
      const float g = z / (1.f + __expf(-z));
      *(unsigned short*)&ygated[tok * LDI + c] = f2bf(yt * g);
    }
  }
}

// ---------------------------------------------------------------- launch
extern "C" void kernel_launch(void* const* d_in, const int* in_sizes, int n_in,
                              void* d_out, int out_size, void* d_ws, size_t ws_size,
                              hipStream_t stream) {
  const float* x      = (const float*)d_in[0];
  const float* W_in   = (const float*)d_in[1];
  const float* conv_w = (const float*)d_in[2];
  const float* conv_b = (const float*)d_in[3];
  const float* W_dt   = (const float*)d_in[4];
  const float* b_dt   = (const float*)d_in[5];
  const float* W_B    = (const float*)d_in[6];
  const float* W_C    = (const float*)d_in[7];
  const float* Dvec   = (const float*)d_in[8];
  const float* W_out  = (const float*)d_in[9];
  float* out = (float*)d_out;

  char* p = (char*)d_ws;
  auto alloc = [&](size_t bytes) {
    char* r = p;
    p += (bytes + 255) & ~(size_t)255;
    return r;
  };
  __hip_bfloat16* xin   = (__hip_bfloat16*)alloc((size_t)NTOK * LDI * 2);  // later ygated
  __hip_bfloat16* zbf   = (__hip_bfloat16*)alloc((size_t)NTOK * LDI * 2);
  char*           scr   = alloc((size_t)NTOK * LDH * 2 + (size_t)2 * INNER * LDH * 2);
  __hip_bfloat16* WmidT = (__hip_bfloat16*)alloc((size_t)NMID * LDI * 2);
  __hip_bfloat16* WoutT = (__hip_bfloat16*)alloc((size_t)HID * LDI * 2);
  unsigned int*   dtx   = (unsigned int*)alloc((size_t)NTOK * LDI * 4);
  float*          Bm    = (float*)alloc((size_t)NTOK * NSTATE * 4);
  float*          Cm    = (float*)alloc((size_t)NTOK * NSTATE * 4);
  float*          cumA  = (float*)alloc((size_t)NTOK * INNER * 4);
  __hip_bfloat16* wT    = (__hip_bfloat16*)alloc((size_t)BATCH * NCHUNK * INNER * TCHUNK * 2);
  __hip_bfloat16* Abuf  = (__hip_bfloat16*)alloc((size_t)BATCH * NCHUNK * 64 * 128 * 2);
  __hip_bfloat16* BtBuf = (__hip_bfloat16*)alloc((size_t)BATCH * NCHUNK * 64 * 64 * 2);
  float*          Pmid  = (float*)alloc((size_t)2 * NTOK * NMID * 4);

  __hip_bfloat16* x_bf   = (__hip_bfloat16*)scr;
  __hip_bfloat16* WinT   = (__hip_bfloat16*)(scr + (size_t)NTOK * LDH * 2);
  __hip_bfloat16* xch    = (__hip_bfloat16*)scr;
  __hip_bfloat16* ygated = xin;
  float*          S      = Pmid;   // after reduce_mid, Pmid dead
  float*          Pout   = Pmid;   // after ypre, S dead

  // 1. conversions / transposes
  cvt_pad_kernel<<<(NTOK * HID / 4 + 255) / 256, 256, 0, stream>>>(x, x_bf, NTOK * HID / 4);
  transpose_cvt_kernel<<<dim3((2 * INNER) / 32, HID / 32), 256, 0, stream>>>(W_in, WinT, HID, 2 * INNER, LDH);
  transpose_cvt_kernel<<<dim3(INNER / 32, INNER / 32), 256, 0, stream>>>(W_dt, WmidT, INNER, INNER, LDI);
  transpose_cvt_kernel<<<dim3(NSTATE / 32, INNER / 32), 256, 0, stream>>>(
      W_B, WmidT + (size_t)INNER * LDI, INNER, NSTATE, LDI);
  transpose_cvt_kernel<<<dim3(NSTATE / 32, INNER / 32), 256, 0, stream>>>(
      W_C, WmidT + (size_t)(INNER + NSTATE) * LDI, INNER, NSTATE, LDI);
  transpose_cvt_kernel<<<dim3(HID / 32, INNER / 32), 256, 0, stream>>>(W_out, WoutT, INNER, HID, LDI);

  // 2. xz = x @ W_in -> split bf16 (xin | z)
  {
    const int gridN = (2 * INNER) / 128, nwg = (NTOK / 128) * gridN;
    gemm_bt_kernel<1><<<nwg, 256, 0, stream>>>(
        x_bf, WinT, NTOK, 2 * INNER, HID, LDH, gridN, nwg, nwg, nullptr, 0, LDI, xin, zbf);
  }

  // 3. conv + silu
  conv_silu_kernel<<<(NTOK * (INNER / 4)) / 256, 256, 0, stream>>>(xin, conv_w, conv_b, xch);

  // 4. mid GEMM split-K x2 + fused reduce/softplus/pack
  {
    const int gridN = NMID / 128;
    const int mnwg = (NTOK / 128) * gridN;
    const int nwg = mnwg * 2;
    gemm_bt_kernel<0><<<nwg, 256, 0, stream>>>(
        xch, WmidT, NTOK, NMID, INNER / 2, LDI, gridN, nwg, mnwg, Pmid, NMID, 0,
        nullptr, nullptr);
    reduce_mid_kernel<<<(NTOK * (NMID / 4)) / 256, 256, 0, stream>>>(Pmid, b_dt, xch, dtx, Bm, Cm);
  }

  // 5. chunked selective scan (GEMM form)
  cumv_kernel<<<dim3(INNER / 256, BATCH * NCHUNK), 256, 0, stream>>>(dtx, cumA, (unsigned int*)wT);
  chunkG_kernel<<<BATCH * NCHUNK, 256, 0, stream>>>(Bm, Cm, Abuf, BtBuf);
  sloc_gemm_kernel<<<BATCH * NCHUNK * 16, 256, 0, stream>>>(wT, BtBuf, cumA, S);
  scan_combine_kernel<<<(BATCH * INNER * NSTATE) / 256, 256, 0, stream>>>(S, cumA);
  ypre_gemm_kernel<<<BATCH * NCHUNK * 16, 256, 0, stream>>>(
      Abuf, wT, S, cumA, xch, zbf, Dvec, ygated);

  // 6. out = ygated @ W_out, split-K x4 + reduce
  {
    const int gridN = HID / 128;
    const int mnwg = (NTOK / 128) * gridN;
    const int nwg = mnwg * 4;
    gemm_bt_kernel<0><<<nwg, 256, 0, stream>>>(
        ygated, WoutT, NTOK, HID, INNER / 4, LDI, gridN, nwg, mnwg, Pout, HID, 0,
        nullptr, nullptr);
    const int n4 = NTOK * HID / 4;
    reduce4_kernel<<<(n4 + 255) / 256, 256, 0, stream>>>(Pout, out, n4);
  }
}

// Round 16
// 308.637 us; speedup vs baseline: 1.2289x; 1.0619x over previous
//
#include <hip/hip_runtime.h>
#include <hip/hip_bf16.h>
#include <math.h>

#define BATCH  2
#define SEQ    2048
#define HID    1024
#define INNER  2048
#define NSTATE 64
#define NTOK   (BATCH * SEQ)
#define TCHUNK 64
#define NCHUNK (SEQ / TCHUNK)
#define NMID   (INNER + 2 * NSTATE)   // 2176
#define LDH    1056
#define LDI    2080

typedef __bf16 bf16x8 __attribute__((ext_vector_type(8)));
typedef float  f32x4  __attribute__((ext_vector_type(4)));

typedef const __attribute__((address_space(1))) char* gas_ptr;
typedef __attribute__((address_space(3))) char*       las_ptr;

__device__ __forceinline__ void gload16(const void* g, void* l) {
  __builtin_amdgcn_global_load_lds((gas_ptr)g, (las_ptr)l, 16, 0, 0);
}

__device__ __forceinline__ unsigned short f2bf(float f) {
  __hip_bfloat16 h = __float2bfloat16(f);
  return __builtin_bit_cast(unsigned short, h);
}
__device__ __forceinline__ float bf2f(unsigned short u) {
  unsigned int x = ((unsigned int)u) << 16;
  return __builtin_bit_cast(float, x);
}

// ---------------------------------------------------------------- cvt fp32->bf16 (padded rows)
__global__ __launch_bounds__(256) void cvt_pad_kernel(
    const float* __restrict__ in, __hip_bfloat16* __restrict__ out, int n4) {
  int i = blockIdx.x * 256 + threadIdx.x;
  if (i >= n4) return;
  const int r = i >> 8;
  const int c = (i & 255) * 4;
  float4 v = *(const float4*)&in[(size_t)r * HID + c];
  ushort4 u;
  u.x = f2bf(v.x); u.y = f2bf(v.y); u.z = f2bf(v.z); u.w = f2bf(v.w);
  *(ushort4*)&out[(size_t)r * LDH + c] = u;
}

// ------------------------------------------------- transpose fp32 [R][C] -> bf16 [C][ostride]
__global__ __launch_bounds__(256) void transpose_cvt_kernel(
    const float* __restrict__ in, __hip_bfloat16* __restrict__ out,
    int R, int C, int ostride) {
  __shared__ float tile[32][33];
  int tx = threadIdx.x & 31, ty = threadIdx.x >> 5;
  int c0 = blockIdx.x * 32, r0 = blockIdx.y * 32;
#pragma unroll
  for (int i = 0; i < 4; ++i)
    tile[ty + 8 * i][tx] = in[(size_t)(r0 + ty + 8 * i) * C + c0 + tx];
  __syncthreads();
#pragma unroll
  for (int i = 0; i < 4; ++i)
    out[(size_t)(c0 + ty + 8 * i) * ostride + r0 + tx] =
        __float2bfloat16(tile[tx][ty + 8 * i]);
}

// ---------------------------------------------------------------- GEMM (r12-proven: 128x128, BK=64)
// EPI 0: fp32 Cout. EPI 1: bf16 split xin|z. EPI 2: bf16 split-K partial to o0 (stride ldc).
template <int EPI>
__global__ __launch_bounds__(256, 4) void gemm_bt_kernel(
    const __hip_bfloat16* __restrict__ A, const __hip_bfloat16* __restrict__ Bt,
    int M, int N, int Klen, int ldk, int gridN, int nwg, int mnwg,
    float* __restrict__ Cout, int ldc, int ldo,
    __hip_bfloat16* __restrict__ o0, __hip_bfloat16* __restrict__ o1) {
  __shared__ __align__(16) __hip_bfloat16 As[128 * 64];
  __shared__ __align__(16) __hip_bfloat16 Bs[128 * 64];
  const int tid = threadIdx.x;
  const int lane = tid & 63;
  const int w = tid >> 6;
  const int wr = w >> 1, wc = w & 1;

  const int orig = blockIdx.x;
  const int q8 = nwg >> 3, r8 = nwg & 7;
  const int xcd = orig & 7, seq = orig >> 3;
  const int wg = (xcd < r8 ? xcd * (q8 + 1) : r8 * (q8 + 1) + (xcd - r8) * q8) + seq;
  const int kz = wg / mnwg;
  const int wgr = wg - kz * mnwg;
  const int m0 = (wgr / gridN) * 128;
  const int n0 = (wgr % gridN) * 128;

  const __hip_bfloat16* Ab = A + (size_t)kz * Klen;
  const __hip_bfloat16* Bb = Bt + (size_t)kz * Klen;

  f32x4 acc[4][4];
#pragma unroll
  for (int i = 0; i < 4; ++i)
#pragma unroll
    for (int j = 0; j < 4; ++j)
#pragma unroll
      for (int r2 = 0; r2 < 4; ++r2) acc[i][j][r2] = 0.f;

  const int g8row = lane >> 3;
  const int scol = ((lane & 7) ^ g8row) * 8;
  const __hip_bfloat16* Agp = Ab + (size_t)(m0 + w * 32 + g8row) * ldk + scol;
  const __hip_bfloat16* Bgp = Bb + (size_t)(n0 + w * 32 + g8row) * ldk + scol;
  __hip_bfloat16* lA = As + (w * 32) * 64;
  __hip_bfloat16* lB = Bs + (w * 32) * 64;

  const int lrow = lane & 15, lk = lane >> 4;
  const int arow0 = wr * 64 + lrow;
  const int brow0 = wc * 64 + lrow;

  const int nt = Klen >> 6;
  for (int t = 0; t < nt; ++t) {
    __syncthreads();
#pragma unroll
    for (int g = 0; g < 4; ++g) {
      gload16(Agp + (size_t)(g * 8) * ldk + t * 64, lA + (g * 8) * 64);
      gload16(Bgp + (size_t)(g * 8) * ldk + t * 64, lB + (g * 8) * 64);
    }
    __syncthreads();
#pragma unroll
    for (int ss = 0; ss < 2; ++ss) {
      bf16x8 af[4], bv[4];
#pragma unroll
      for (int i = 0; i < 4; ++i) {
        const int ra = arow0 + i * 16;
        af[i] = *(const bf16x8*)(As + ra * 64 + (((ss * 4 + lk) ^ (ra & 7)) * 8));
        const int rb = brow0 + i * 16;
        bv[i] = *(const bf16x8*)(Bs + rb * 64 + (((ss * 4 + lk) ^ (rb & 7)) * 8));
      }
#pragma unroll
      for (int i = 0; i < 4; ++i)
#pragma unroll
        for (int j = 0; j < 4; ++j)
          acc[i][j] = __builtin_amdgcn_mfma_f32_16x16x32_bf16(af[i], bv[j], acc[i][j], 0, 0, 0);
    }
  }

#pragma unroll
  for (int i = 0; i < 4; ++i) {
#pragma unroll
    for (int j = 0; j < 4; ++j) {
#pragma unroll
      for (int r2 = 0; r2 < 4; ++r2) {
        const int row = m0 + wr * 64 + i * 16 + lk * 4 + r2;
        const int col = n0 + wc * 64 + j * 16 + lrow;
        const float v = acc[i][j][r2];
        if constexpr (EPI == 0) {
          Cout[(size_t)kz * M * ldc + (size_t)row * ldc + col] = v;
        } else if constexpr (EPI == 1) {
          if (col < INNER) o0[(size_t)row * ldo + col] = __float2bfloat16(v);
          else             o1[(size_t)row * ldo + (col - INNER)] = __float2bfloat16(v);
        } else {
          o0[(size_t)kz * M * ldc + (size_t)row * ldc + col] = __float2bfloat16(v);
        }
      }
    }
  }
}

// ---------------------------------------------------------------- mid reduce: bf16 P0+P1 -> packed(dt,xc) | Bm | Cm
__global__ __launch_bounds__(256) void reduce_mid_kernel(
    const __hip_bfloat16* __restrict__ P, const float* __restrict__ bdt,
    const __hip_bfloat16* __restrict__ xch, unsigned int* __restrict__ dtx,
    float* __restrict__ Bm, float* __restrict__ Cm) {
  const int i = blockIdx.x * 256 + threadIdx.x;
  const int row = i / (NMID / 4);
  const int c4 = i - row * (NMID / 4);
  const int col = c4 * 4;
  float4 v = make_float4(0.f, 0.f, 0.f, 0.f);
#pragma unroll
  for (int pp = 0; pp < 2; ++pp) {
    const ushort4 u = *(const ushort4*)&P[(size_t)pp * NTOK * NMID + (size_t)row * NMID + col];
    v.x += bf2f(u.x); v.y += bf2f(u.y); v.z += bf2f(u.z); v.w += bf2f(u.w);
  }
  if (col < INNER) {
    float4 bb = *(const float4*)&bdt[col];
    float4 d;
    d.x = v.x + bb.x; d.y = v.y + bb.y; d.z = v.z + bb.z; d.w = v.w + bb.w;
    d.x = (d.x > 15.f) ? d.x : log1pf(__expf(d.x));
    d.y = (d.y > 15.f) ? d.y : log1pf(__expf(d.y));
    d.z = (d.z > 15.f) ? d.z : log1pf(__expf(d.z));
    d.w = (d.w > 15.f) ? d.w : log1pf(__expf(d.w));
    ushort4 xv = *(const ushort4*)&xch[(size_t)row * LDI + col];
    uint4 o;
    o.x = (unsigned int)f2bf(d.x) | ((unsigned int)xv.x << 16);
    o.y = (unsigned int)f2bf(d.y) | ((unsigned int)xv.y << 16);
    o.z = (unsigned int)f2bf(d.z) | ((unsigned int)xv.z << 16);
    o.w = (unsigned int)f2bf(d.w) | ((unsigned int)xv.w << 16);
    *(uint4*)&dtx[(size_t)row * LDI + col] = o;
  } else if (col < INNER + NSTATE) {
    *(float4*)&Bm[(size_t)row * NSTATE + (col - INNER)] = v;
  } else {
    *(float4*)&Cm[(size_t)row * NSTATE + (col - INNER - NSTATE)] = v;
  }
}

// ---------------------------------------------------------------- split-K4 reduce (bf16 partials -> fp32 out)
__global__ __launch_bounds__(256) void reduce4b_kernel(
    const __hip_bfloat16* __restrict__ P, float* __restrict__ out, int n4) {
  int i = blockIdx.x * 256 + threadIdx.x;
  if (i >= n4) return;
  float4 acc = make_float4(0.f, 0.f, 0.f, 0.f);
#pragma unroll
  for (int pp = 0; pp < 4; ++pp) {
    ushort4 u = ((const ushort4*)P)[(size_t)pp * n4 + i];
    acc.x += bf2f(u.x); acc.y += bf2f(u.y); acc.z += bf2f(u.z); acc.w += bf2f(u.w);
  }
  ((float4*)out)[i] = acc;
}

// ---------------------------------------------------------------- causal depthwise conv + silu
__global__ __launch_bounds__(256) void conv_silu_kernel(
    const __hip_bfloat16* __restrict__ xin, const float* __restrict__ cw,
    const float* __restrict__ cb, __hip_bfloat16* __restrict__ xch) {
  int idx = blockIdx.x * 256 + threadIdx.x;
  int cg = idx & 511;
  int tok = idx >> 9;
  int c = cg * 4;
  int l = tok & (SEQ - 1);
  float wv[4][4];
#pragma unroll
  for (int i = 0; i < 4; ++i) {
    float4 w = *(const float4*)&cw[(c + i) * 4];
    wv[i][0] = w.x; wv[i][1] = w.y; wv[i][2] = w.z; wv[i][3] = w.w;
  }
  float4 bias = *(const float4*)&cb[c];
  float r0 = bias.x, r1 = bias.y, r2 = bias.z, r3 = bias.w;
#pragma unroll
  for (int k = 0; k < 4; ++k) {
    const int d = 3 - k;
    if (l >= d) {
      ushort4 xv = *(const ushort4*)&xin[(size_t)(tok - d) * LDI + c];
      r0 = fmaf(bf2f(xv.x), wv[0][k], r0);
      r1 = fmaf(bf2f(xv.y), wv[1][k], r1);
      r2 = fmaf(bf2f(xv.z), wv[2][k], r2);
      r3 = fmaf(bf2f(xv.w), wv[3][k], r3);
    }
  }
  r0 = r0 / (1.f + __expf(-r0));
  r1 = r1 / (1.f + __expf(-r1));
  r2 = r2 / (1.f + __expf(-r2));
  r3 = r3 / (1.f + __expf(-r3));
  ushort4 u;
  u.x = f2bf(r0); u.y = f2bf(r1); u.z = f2bf(r2); u.w = f2bf(r3);
  *(ushort4*)&xch[(size_t)tok * LDI + c] = u;
}

// ---------------------------------------------------------------- cumA (bf16) + w (chunked decay factors)
__global__ __launch_bounds__(256) void cumv_kernel(
    const unsigned int* __restrict__ dtx, unsigned short* __restrict__ cumA,
    unsigned int* __restrict__ wT) {
  const int bk = blockIdx.y;
  const int c = blockIdx.x * 256 + threadIdx.x;
  const int b = bk >> 5, k = bk & 31;
  const size_t tokbase = (size_t)(b * SEQ + k * TCHUNK);
  float cum = 1.f;
  unsigned int wreg[32];
#pragma unroll
  for (int t = 0; t < TCHUNK; ++t) {
    const unsigned int pk = dtx[(tokbase + t) * LDI + c];
    const float dtv = bf2f((unsigned short)(pk & 0xffffu));
    const float xc = bf2f((unsigned short)(pk >> 16));
    cum *= __expf(-dtv);
    cum = fmaxf(cum, 1e-30f);
    cumA[(tokbase + t) * INNER + c] = f2bf(cum);
    const unsigned short wb = f2bf(dtv * xc / cum);
    if (t & 1) wreg[t >> 1] |= ((unsigned int)wb) << 16;
    else       wreg[t >> 1] = (unsigned int)wb;
  }
  uint4* dst = (uint4*)(wT + ((size_t)bk * INNER + c) * 32);
#pragma unroll
  for (int j = 0; j < 8; ++j)
    dst[j] = make_uint4(wreg[4 * j], wreg[4 * j + 1], wreg[4 * j + 2], wreg[4 * j + 3]);
}

// ---------------------------------------------------------------- per-chunk G = tril(C@B^T), + bf16 C / B^T copies
__global__ __launch_bounds__(256) void chunkG_kernel(
    const float* __restrict__ Bm, const float* __restrict__ Cm,
    __hip_bfloat16* __restrict__ Abuf, __hip_bfloat16* __restrict__ BtBuf) {
  __shared__ float Bsh[TCHUNK][NSTATE + 4];
  __shared__ float Csh[TCHUNK][NSTATE + 4];
  const int bk = blockIdx.x;
  const int b = bk >> 5, k = bk & 31;
  const int tid = threadIdx.x;
  const size_t tokbase = (size_t)(b * SEQ + k * TCHUNK);
  for (int i = tid; i < TCHUNK * 16; i += 256) {
    const int row = i >> 4, q = i & 15;
    *(float4*)&Bsh[row][q * 4] = *(const float4*)&Bm[(tokbase + row) * NSTATE + q * 4];
    *(float4*)&Csh[row][q * 4] = *(const float4*)&Cm[(tokbase + row) * NSTATE + q * 4];
  }
  __syncthreads();
  for (int e = tid; e < 64 * 64; e += 256) {
    const int t = e >> 6, tau = e & 63;
    float g = 0.f;
    if (tau <= t) {
#pragma unroll
      for (int q = 0; q < 16; ++q) {
        const float4 cv = *(const float4*)&Csh[t][q * 4];
        const float4 bv = *(const float4*)&Bsh[tau][q * 4];
        g += cv.x * bv.x + cv.y * bv.y + cv.z * bv.z + cv.w * bv.w;
      }
    }
    Abuf[((size_t)bk * 64 + t) * 128 + tau] = __float2bfloat16(g);
  }
  for (int e = tid; e < 64 * 64; e += 256) {
    const int n2 = e >> 6, r = e & 63;
    BtBuf[((size_t)bk * 64 + n2) * 64 + r] = __float2bfloat16(Bsh[r][n2]);
    Abuf[((size_t)bk * 64 + n2) * 128 + 64 + r] = __float2bfloat16(Csh[n2][r]);
  }
}

// ---------------------------------------------------------------- S_loc GEMM: S[bk][c][n] (bf16) = cumA_T[c]*(wT@BtBuf^T)
__global__ __launch_bounds__(256, 4) void sloc_gemm_kernel(
    const __hip_bfloat16* __restrict__ wT, const __hip_bfloat16* __restrict__ BtBuf,
    const unsigned short* __restrict__ cumA, unsigned short* __restrict__ S) {
  __shared__ __align__(16) __hip_bfloat16 As[128 * 64];
  __shared__ __align__(16) __hip_bfloat16 Bs[64 * 64];
  const int tid = threadIdx.x;
  const int lane = tid & 63;
  const int w = tid >> 6;
  const int bk = blockIdx.x >> 4;
  const int ct = blockIdx.x & 15;
  const int b = bk >> 5, k = bk & 31;
  const int c0 = ct * 128;

  const int g8row = lane >> 3;
  const int scol = ((lane & 7) ^ g8row) * 8;
  const __hip_bfloat16* Ag = wT + ((size_t)bk * INNER + c0 + w * 32 + g8row) * 64 + scol;
  const __hip_bfloat16* Bg = BtBuf + ((size_t)bk * 64 + w * 16 + g8row) * 64 + scol;
  __hip_bfloat16* lA = As + (w * 32) * 64;
  __hip_bfloat16* lB = Bs + (w * 16) * 64;
#pragma unroll
  for (int g = 0; g < 4; ++g) gload16(Ag + (size_t)(g * 8) * 64, lA + (g * 8) * 64);
#pragma unroll
  for (int g = 0; g < 2; ++g) gload16(Bg + (size_t)(g * 8) * 64, lB + (g * 8) * 64);
  __syncthreads();

  const int lrow = lane & 15, lk = lane >> 4;
  f32x4 acc[2][4];
#pragma unroll
  for (int i = 0; i < 2; ++i)
#pragma unroll
    for (int j = 0; j < 4; ++j)
#pragma unroll
      for (int r2 = 0; r2 < 4; ++r2) acc[i][j][r2] = 0.f;

#pragma unroll
  for (int ss = 0; ss < 2; ++ss) {
    bf16x8 af[2], bv[4];
#pragma unroll
    for (int i = 0; i < 2; ++i) {
      const int ra = w * 32 + i * 16 + lrow;
      af[i] = *(const bf16x8*)(As + ra * 64 + (((ss * 4 + lk) ^ (ra & 7)) * 8));
    }
#pragma unroll
    for (int j = 0; j < 4; ++j) {
      const int rb = j * 16 + lrow;
      bv[j] = *(const bf16x8*)(Bs + rb * 64 + (((ss * 4 + lk) ^ (rb & 7)) * 8));
    }
#pragma unroll
    for (int i = 0; i < 2; ++i)
#pragma unroll
      for (int j = 0; j < 4; ++j)
        acc[i][j] = __builtin_amdgcn_mfma_f32_16x16x32_bf16(af[i], bv[j], acc[i][j], 0, 0, 0);
  }

  const size_t tokT = (size_t)(b * SEQ + k * TCHUNK + 63);
#pragma unroll
  for (int i = 0; i < 2; ++i) {
#pragma unroll
    for (int j = 0; j < 4; ++j) {
#pragma unroll
      for (int r2 = 0; r2 < 4; ++r2) {
        const int c = c0 + w * 32 + i * 16 + lk * 4 + r2;
        const int n = j * 16 + lrow;
        const float sc = bf2f(cumA[tokT * INNER + c]);
        S[((size_t)bk * INNER + c) * 64 + n] = f2bf(acc[i][j][r2] * sc);
      }
    }
  }
}

// ---------------------------------------------------------------- cross-chunk combine (in place, bf16 S)
__global__ __launch_bounds__(256) void scan_combine_kernel(
    unsigned short* __restrict__ S, const unsigned short* __restrict__ cumA) {
  const int idx = blockIdx.x * 256 + threadIdx.x;
  const int n = idx & 63;
  const int c = (idx >> 6) & (INNER - 1);
  const int b = idx >> 17;
  float s = 0.f;
  for (int k = 0; k < NCHUNK; ++k) {
    const size_t cs = (size_t)(b * NCHUNK + k) * INNER + c;
    const size_t off = cs * 64 + n;
    const float loc = bf2f(S[off]);
    S[off] = f2bf(s);
    const float ak = bf2f(cumA[((size_t)(b * SEQ + k * TCHUNK + 63)) * INNER + c]);
    s = fmaf(ak, s, loc);
  }
}

// ---------------------------------------------------------------- y GEMM: [trilG|C] @ [wT;S_in] -> epilogue
__global__ __launch_bounds__(256, 4) void ypre_gemm_kernel(
    const __hip_bfloat16* __restrict__ Abuf, const __hip_bfloat16* __restrict__ wT,
    const unsigned short* __restrict__ S, const unsigned short* __restrict__ cumA,
    const __hip_bfloat16* __restrict__ xch, const __hip_bfloat16* __restrict__ zbf,
    const float* __restrict__ Dv, __hip_bfloat16* __restrict__ ygated) {
  __shared__ __align__(16) __hip_bfloat16 Asm[64 * 128];   // [t][k]
  __shared__ __align__(16) __hip_bfloat16 Bsm[128 * 128];  // [c][k]
  const int tid = threadIdx.x;
  const int lane = tid & 63;
  const int w = tid >> 6;
  const int bk = blockIdx.x >> 4;
  const int ct = blockIdx.x & 15;
  const int b = bk >> 5, k = bk & 31;
  const int c0 = ct * 128;

  {
#pragma unroll
    for (int g = 0; g < 4; ++g) {
      const int base = w * 16 + g * 4;
      const int col16s = (lane & 15) ^ ((base + (lane >> 4)) & 7);
      const __hip_bfloat16* src =
          Abuf + ((size_t)bk * 64 + base + (lane >> 4)) * 128 + col16s * 8;
      gload16(src, (char*)Asm + base * 256);
    }
  }
  {
    const int row = tid & 127, part = tid >> 7;
    const int c = c0 + row;
    if (part == 0) {
      const uint4* src = (const uint4*)(wT + ((size_t)bk * INNER + c) * 64);
#pragma unroll
      for (int s2 = 0; s2 < 8; ++s2) {
        uint4 v = src[s2];
        *(uint4*)((char*)Bsm + row * 256 + (s2 ^ (row & 7)) * 16) = v;
      }
    } else {
      const uint4* srcS = (const uint4*)(S + ((size_t)bk * INNER + c) * 64);
#pragma unroll
      for (int s2 = 0; s2 < 8; ++s2) {
        uint4 v = srcS[s2];
        *(uint4*)((char*)Bsm + row * 256 + ((8 + s2) ^ (row & 7)) * 16) = v;
      }
    }
  }
  __syncthreads();

  const int lrow = lane & 15, lk = lane >> 4;
  f32x4 acc[8];
#pragma unroll
  for (int j = 0; j < 8; ++j)
#pragma unroll
    for (int r2 = 0; r2 < 4; ++r2) acc[j][r2] = 0.f;

  const int ra = w * 16 + lrow;
#pragma unroll
  for (int kk = 0; kk < 4; ++kk) {
    const int csa = (kk * 4 + lk) ^ (ra & 7);
    bf16x8 af = *(const bf16x8*)((const char*)Asm + ra * 256 + csa * 16);
#pragma unroll
    for (int j = 0; j < 8; ++j) {
      const int rb = j * 16 + lrow;
      const int csb = (kk * 4 + lk) ^ (rb & 7);
      bf16x8 bv = *(const bf16x8*)((const char*)Bsm + rb * 256 + csb * 16);
      acc[j] = __builtin_amdgcn_mfma_f32_16x16x32_bf16(af, bv, acc[j], 0, 0, 0);
    }
  }

  const size_t tokb = (size_t)(b * SEQ + k * TCHUNK);
#pragma unroll
  for (int j = 0; j < 8; ++j) {
#pragma unroll
    for (int r2 = 0; r2 < 4; ++r2) {
      const int t = w * 16 + lk * 4 + r2;
      const int c = c0 + j * 16 + lrow;
      const size_t tok = tokb + t;
      const float ca = bf2f(cumA[tok * INNER + c]);
      const float xc = bf2f(*(const unsigned short*)&xch[tok * LDI + c]);
      const float z = bf2f(*(const unsigned short*)&zbf[tok * LDI + c]);
      const float yt = ca * acc[j][r2] + Dv[c] * xc;
      const float g = z / (1.f + __expf(-z));
      *(unsigned short*)&ygated[tok * LDI + c] = f2bf(yt * g);
    }
  }
}

// ---------------------------------------------------------------- launch
extern "C" void kernel_launch(void* const* d_in, const int* in_sizes, int n_in,
                              void* d_out, int out_size, void* d_ws, size_t ws_size,
                              hipStream_t stream) {
  const float* x      = (const float*)d_in[0];
  const float* W_in   = (const float*)d_in[1];
  const float* conv_w = (const float*)d_in[2];
  const float* conv_b = (const float*)d_in[3];
  const float* W_dt   = (const float*)d_in[4];
  const float* b_dt   = (const float*)d_in[5];
  const float* W_B    = (const float*)d_in[6];
  const float* W_C    = (const float*)d_in[7];
  const float* Dvec   = (const float*)d_in[8];
  const float* W_out  = (const float*)d_in[9];
  float* out = (float*)d_out;

  char* p = (char*)d_ws;
  auto alloc = [&](size_t bytes) {
    char* r = p;
    p += (bytes + 255) & ~(size_t)255;
    return r;
  };
  __hip_bfloat16* xin   = (__hip_bfloat16*)alloc((size_t)NTOK * LDI * 2);  // later ygated
  __hip_bfloat16* zbf   = (__hip_bfloat16*)alloc((size_t)NTOK * LDI * 2);
  char*           scr   = alloc((size_t)NTOK * LDH * 2 + (size_t)2 * INNER * LDH * 2);
  __hip_bfloat16* WmidT = (__hip_bfloat16*)alloc((size_t)NMID * LDI * 2);
  __hip_bfloat16* WoutT = (__hip_bfloat16*)alloc((size_t)HID * LDI * 2);
  unsigned int*   dtx   = (unsigned int*)alloc((size_t)NTOK * LDI * 4);
  float*          Bm    = (float*)alloc((size_t)NTOK * NSTATE * 4);
  float*          Cm    = (float*)alloc((size_t)NTOK * NSTATE * 4);
  unsigned short* cumA  = (unsigned short*)alloc((size_t)NTOK * INNER * 2);
  __hip_bfloat16* wT    = (__hip_bfloat16*)alloc((size_t)BATCH * NCHUNK * INNER * TCHUNK * 2);
  __hip_bfloat16* Abuf  = (__hip_bfloat16*)alloc((size_t)BATCH * NCHUNK * 64 * 128 * 2);
  __hip_bfloat16* BtBuf = (__hip_bfloat16*)alloc((size_t)BATCH * NCHUNK * 64 * 64 * 2);
  __hip_bfloat16* Pmid  = (__hip_bfloat16*)alloc((size_t)2 * NTOK * NMID * 2);  // 35.7MB; later S / Pout

  __hip_bfloat16* x_bf   = (__hip_bfloat16*)scr;
  __hip_bfloat16* WinT   = (__hip_bfloat16*)(scr + (size_t)NTOK * LDH * 2);
  __hip_bfloat16* xch    = (__hip_bfloat16*)scr;
  __hip_bfloat16* ygated = xin;
  unsigned short* S      = (unsigned short*)Pmid;  // 16MB, after reduce_mid
  __hip_bfloat16* Pout   = Pmid;                   // 33.5MB, after ypre

  // 1. conversions / transposes
  cvt_pad_kernel<<<(NTOK * HID / 4 + 255) / 256, 256, 0, stream>>>(x, x_bf, NTOK * HID / 4);
  transpose_cvt_kernel<<<dim3((2 * INNER) / 32, HID / 32), 256, 0, stream>>>(W_in, WinT, HID, 2 * INNER, LDH);
  transpose_cvt_kernel<<<dim3(INNER / 32, INNER / 32), 256, 0, stream>>>(W_dt, WmidT, INNER, INNER, LDI);
  transpose_cvt_kernel<<<dim3(NSTATE / 32, INNER / 32), 256, 0, stream>>>(
      W_B, WmidT + (size_t)INNER * LDI, INNER, NSTATE, LDI);
  transpose_cvt_kernel<<<dim3(NSTATE / 32, INNER / 32), 256, 0, stream>>>(
      W_C, WmidT + (size_t)(INNER + NSTATE) * LDI, INNER, NSTATE, LDI);
  transpose_cvt_kernel<<<dim3(HID / 32, INNER / 32), 256, 0, stream>>>(W_out, WoutT, INNER, HID, LDI);

  // 2. xz = x @ W_in -> split bf16 (xin | z)
  {
    const int gridN = (2 * INNER) / 128, nwg = (NTOK / 128) * gridN;
    gemm_bt_kernel<1><<<nwg, 256, 0, stream>>>(
        x_bf, WinT, NTOK, 2 * INNER, HID, LDH, gridN, nwg, nwg, nullptr, 0, LDI, xin, zbf);
  }

  // 3. conv + silu
  conv_silu_kernel<<<(NTOK * (INNER / 4)) / 256, 256, 0, stream>>>(xin, conv_w, conv_b, xch);

  // 4. mid GEMM split-K x2 (bf16 partials) + fused reduce/softplus/pack
  {
    const int gridN = NMID / 128;
    const int mnwg = (NTOK / 128) * gridN;
    const int nwg = mnwg * 2;
    gemm_bt_kernel<2><<<nwg, 256, 0, stream>>>(
        xch, WmidT, NTOK, NMID, INNER / 2, LDI, gridN, nwg, mnwg, nullptr, NMID, 0,
        Pmid, nullptr);
    reduce_mid_kernel<<<(NTOK * (NMID / 4)) / 256, 256, 0, stream>>>(Pmid, b_dt, xch, dtx, Bm, Cm);
  }

  // 5. chunked selective scan (GEMM form, bf16 intermediates)
  cumv_kernel<<<dim3(INNER / 256, BATCH * NCHUNK), 256, 0, stream>>>(dtx, cumA, (unsigned int*)wT);
  chunkG_kernel<<<BATCH * NCHUNK, 256, 0, stream>>>(Bm, Cm, Abuf, BtBuf);
  sloc_gemm_kernel<<<BATCH * NCHUNK * 16, 256, 0, stream>>>(wT, BtBuf, cumA, S);
  scan_combine_kernel<<<(BATCH * INNER * NSTATE) / 256, 256, 0, stream>>>(S, cumA);
  ypre_gemm_kernel<<<BATCH * NCHUNK * 16, 256, 0, stream>>>(
      Abuf, wT, S, cumA, xch, zbf, Dvec, ygated);

  // 6. out = ygated @ W_out, split-K x4 (bf16 partials) + reduce
  {
    const int gridN = HID / 128;
    const int mnwg = (NTOK / 128) * gridN;
    const int nwg = mnwg * 4;
    gemm_bt_kernel<2><<<nwg, 256, 0, stream>>>(
        ygated, WoutT, NTOK, HID, INNER / 4, LDI, gridN, nwg, mnwg, nullptr, HID, 0,
        Pout, nullptr);
    const int n4 = NTOK * HID / 4;
    reduce4b_kernel<<<(n4 + 255) / 256, 256, 0, stream>>>(Pout, out, n4);
  }
}